// Round 1
// baseline (488.497 us; speedup 1.0000x reference)
//
#include <hip/hip_runtime.h>
#include <hip/hip_bf16.h>

typedef unsigned short u16;
typedef __attribute__((ext_vector_type(4))) float f32x4;
typedef __attribute__((ext_vector_type(8))) short s16x8;

#define NB 4
#define TTOK 1024
#define DD 1024
#define NH 16
#define HD 64
#define MT 4096      // B*T tokens
#define NCH 16       // chunks per (b,h)
#define CLEN 64      // chunk length

static __device__ __forceinline__ float b2f(u16 u) {
  union { unsigned int u; float f; } c; c.u = ((unsigned int)u) << 16; return c.f;
}
static __device__ __forceinline__ u16 f2b(float f) {
  union { float f; unsigned int u; } c; c.f = f;
  return (u16)((c.u + 0x7fffu + ((c.u >> 16) & 1u)) >> 16);
}
static __device__ __forceinline__ float rdl(float v, int i) {
  union { float f; int s; } c; c.f = v;
  union { int s; float f; } o; o.s = __builtin_amdgcn_readlane(c.s, i);
  return o.f;
}

// ---------------- weight conversion / packing ----------------
__global__ __launch_bounds__(256) void convW(const float* __restrict__ s0, const float* __restrict__ s1,
                                             const float* __restrict__ s2, const float* __restrict__ s3,
                                             const float* __restrict__ s4, u16* __restrict__ dst) {
  long f = ((long)blockIdx.x * 256 + threadIdx.x) << 2;   // 5 * 1048576 elems
  int sel = (int)(f >> 20);
  const float* s = sel == 0 ? s0 : sel == 1 ? s1 : sel == 2 ? s2 : sel == 3 ? s3 : s4;
  long off = f & 1048575;
  f32x4 v = *(const f32x4*)&s[off];
  ushort4 o; o.x = f2b(v[0]); o.y = f2b(v[1]); o.z = f2b(v[2]); o.w = f2b(v[3]);
  *(ushort4*)&dst[f] = o;
}

__global__ __launch_bounds__(256) void convLora(
    const float* a0, const float* a1, const float* a2, const float* a3, const float* a4,
    const float* b0, const float* b1, const float* b2, const float* b3, const float* b4,
    const float* l0, const float* l1, const float* l2, const float* l3, const float* l4,
    u16* __restrict__ laD, u16* __restrict__ lbD, float* __restrict__ llD) {
  long f = ((long)blockIdx.x * 256 + threadIdx.x) << 2;
  if (f < 327680) {            // 5 x 65536 la
    int sel = (int)(f >> 16); long off = f & 65535;
    const float* s = sel == 0 ? a0 : sel == 1 ? a1 : sel == 2 ? a2 : sel == 3 ? a3 : a4;
    f32x4 v = *(const f32x4*)&s[off];
    ushort4 o; o.x = f2b(v[0]); o.y = f2b(v[1]); o.z = f2b(v[2]); o.w = f2b(v[3]);
    *(ushort4*)&laD[f] = o;
  } else if (f < 655360) {     // 5 x 65536 lb
    long g = f - 327680;
    int sel = (int)(g >> 16); long off = g & 65535;
    const float* s = sel == 0 ? b0 : sel == 1 ? b1 : sel == 2 ? b2 : sel == 3 ? b3 : b4;
    f32x4 v = *(const f32x4*)&s[off];
    ushort4 o; o.x = f2b(v[0]); o.y = f2b(v[1]); o.z = f2b(v[2]); o.w = f2b(v[3]);
    *(ushort4*)&lbD[g] = o;
  } else if (f < 660480) {     // 5 x 1024 ll (f32 copy)
    long g = f - 655360;
    int sel = (int)(g >> 10); long off = g & 1023;
    const float* s = sel == 0 ? l0 : sel == 1 ? l1 : sel == 2 ? l2 : sel == 3 ? l3 : l4;
    *(f32x4*)&llD[g] = *(const f32x4*)&s[off];
  }
}

// ---------------- token shift prep: dx (f32), lerpx (bf16) ----------------
__global__ __launch_bounds__(256) void prep(const float* __restrict__ x, const float* __restrict__ xw,
                                            u16* __restrict__ lerpx, float* __restrict__ dxP) {
  long f = ((long)blockIdx.x * 256 + threadIdx.x) << 2;
  int d = (int)(f & (DD - 1));
  int m = (int)(f >> 10);
  int t = m & (TTOK - 1);
  f32x4 xv = *(const f32x4*)&x[f];
  f32x4 xm = {};
  if (t > 0) xm = *(const f32x4*)&x[f - DD];
  f32x4 xwv = *(const f32x4*)&xw[d];
  f32x4 dx = xm - xv;
  f32x4 lp = xv + dx * xwv;
  *(f32x4*)&dxP[f] = dx;
  ushort4 o; o.x = f2b(lp[0]); o.y = f2b(lp[1]); o.z = f2b(lp[2]); o.w = f2b(lp[3]);
  *(ushort4*)&lerpx[f] = o;
}

// ---------------- generic bf16 MFMA GEMM: C[m][n] = sum_k A[m][k]*B[n][k] ----------------
// EPI: 0 = store f32; 1 = store bf16(tanh); 2 = z-epilogue bf16(x + dx*(ll+acc));
//      3 = store f32 exp(-exp(ll+acc)); 4 = store bf16
template<int BM, int BN, int EPI>
__launch_bounds__(256)
__global__ void gemm_bt(const u16* __restrict__ Ab, long sAz,
                        const u16* __restrict__ Bb, long sBz,
                        void* __restrict__ Ob, long sOz,
                        const float* __restrict__ llb,
                        const float* __restrict__ xP,
                        const float* __restrict__ dxP,
                        int M, int N, int K) {
  constexpr int BK = 32;
  constexpr int LDT = 40;                       // +8 elem pad: 80B row stride, ~2-way bank alias (free)
  __shared__ __align__(16) u16 As[BM * LDT];
  __shared__ __align__(16) u16 Bs[BN * LDT];
  const int z = blockIdx.z;
  const u16* A = Ab + (long)z * sAz;
  const u16* Bw = Bb + (long)z * sBz;
  const int m0 = blockIdx.y * BM;
  const int n0 = blockIdx.x * BN;
  const int tid = threadIdx.x;
  const int wv = tid >> 6;
  const int l = tid & 63;
  constexpr int WM = BM / 2, WN = BN / 2;
  constexpr int FM = WM / 16, FN = WN / 16;
  const int wm0 = (wv >> 1) * WM, wn0 = (wv & 1) * WN;
  const int lrow = l & 15, lk = (l >> 4) * 8;
  f32x4 acc[FM][FN] = {};
  for (int k0 = 0; k0 < K; k0 += BK) {
    __syncthreads();
#pragma unroll
    for (int c = 0; c < BM * 4 / 256; ++c) {
      int cc = tid + c * 256;
      int r = cc >> 2, kc = (cc & 3) << 3;
      *(s16x8*)&As[r * LDT + kc] = *(const s16x8*)&A[(long)(m0 + r) * K + (k0 + kc)];
    }
#pragma unroll
    for (int c = 0; c < BN * 4 / 256; ++c) {
      int cc = tid + c * 256;
      int r = cc >> 2, kc = (cc & 3) << 3;
      *(s16x8*)&Bs[r * LDT + kc] = *(const s16x8*)&Bw[(long)(n0 + r) * K + (k0 + kc)];
    }
    __syncthreads();
    s16x8 af[FM], bfr[FN];
#pragma unroll
    for (int m = 0; m < FM; ++m) af[m] = *(const s16x8*)&As[(wm0 + m * 16 + lrow) * LDT + lk];
#pragma unroll
    for (int n = 0; n < FN; ++n) bfr[n] = *(const s16x8*)&Bs[(wn0 + n * 16 + lrow) * LDT + lk];
#pragma unroll
    for (int m = 0; m < FM; ++m)
#pragma unroll
      for (int n = 0; n < FN; ++n)
        acc[m][n] = __builtin_amdgcn_mfma_f32_16x16x32_bf16(af[m], bfr[n], acc[m][n], 0, 0, 0);
  }
#pragma unroll
  for (int m = 0; m < FM; ++m) {
#pragma unroll
    for (int n = 0; n < FN; ++n) {
      const int j = n0 + wn0 + n * 16 + lrow;
#pragma unroll
      for (int q = 0; q < 4; ++q) {
        const int i = m0 + wm0 + m * 16 + (l >> 4) * 4 + q;
        const long off = (long)i * N + j;
        float v = acc[m][n][q];
        if constexpr (EPI == 0) {
          ((float*)Ob + (long)z * sOz)[off] = v;
        } else if constexpr (EPI == 1) {
          ((u16*)Ob + (long)z * sOz)[off] = f2b(tanhf(v));
        } else if constexpr (EPI == 2) {
          float val = xP[off] + dxP[off] * (llb[(long)z * N + j] + v);
          ((u16*)Ob + (long)z * sOz)[off] = f2b(val);
        } else if constexpr (EPI == 3) {
          ((float*)Ob + (long)z * sOz)[off] = expf(-expf(llb[j] + v));
        } else {
          ((u16*)Ob + (long)z * sOz)[off] = f2b(v);
        }
      }
    }
  }
}

// ---------------- S1: chunk-local WKV scan (S0 = 0), 1 wave/block ----------------
__global__ __launch_bounds__(64) void scan_local(
    const u16* __restrict__ rP, const u16* __restrict__ kP,
    const u16* __restrict__ vP, const float* __restrict__ wP,
    const float* __restrict__ uP, float* __restrict__ ys,
    u16* __restrict__ rtil, float* __restrict__ SL, float* __restrict__ AC) {
  const int bhc = blockIdx.x;
  const int c = bhc & (NCH - 1), h = (bhc >> 4) & (NH - 1), b = bhc >> 8;
  const int j = threadIdx.x;
  float s[64];
#pragma unroll
  for (int i = 0; i < 64; ++i) s[i] = 0.f;
  float Aj = 1.f;
  const float uj = uP[h * HD + j];
  long base = ((long)(b * TTOK + c * CLEN) * DD) + h * HD;
  float rj = b2f(rP[base + j]), kj = b2f(kP[base + j]);
  float vj = b2f(vP[base + j]), wj = wP[base + j];
  for (int tt = 0; tt < CLEN; ++tt) {
    const long nbase = base + DD;
    float rn = 0.f, kn = 0.f, vn = 0.f, wn = 0.f;
    if (tt + 1 < CLEN) {      // prefetch next step
      rn = b2f(rP[nbase + j]); kn = b2f(kP[nbase + j]);
      vn = b2f(vP[nbase + j]); wn = wP[nbase + j];
    }
    rtil[base + j] = f2b(rj * Aj);     // r_t * A_{t-1} (before this step's decay)
    float y = 0.f;
#pragma unroll
    for (int i = 0; i < 64; ++i) {
      const float ri = rdl(rj, i);
      const float ki = rdl(kj, i);
      const float wi = rdl(wj, i);
      const float ui = rdl(uj, i);
      const float kv = ki * vj;
      y = fmaf(ri, fmaf(ui, kv, s[i]), y);
      s[i] = fmaf(wi, s[i], kv);
    }
    ys[base + j] = y;
    Aj *= wj;
    base = nbase;
    rj = rn; kj = kn; vj = vn; wj = wn;
  }
#pragma unroll
  for (int i = 0; i < 64; ++i) SL[((long)bhc * 64 + i) * 64 + j] = s[i];
  AC[(long)bhc * 64 + j] = Aj;
}

// ---------------- S2a: propagate chunk-boundary states; overwrite SL[c] with S_in(c) ----------------
__global__ __launch_bounds__(256) void scan_prop(
    float* __restrict__ SL, const float* __restrict__ AC,
    const float* __restrict__ initS, float* __restrict__ st1) {
  const int bh = blockIdx.x;          // b*16 + h
  const int h = bh & (NH - 1);
  const int tid = threadIdx.x;
  const int i = tid >> 2, jg = (tid & 3) * 16;
  f32x4 sin4[4];
  const f32x4* ip = (const f32x4*)(initS + ((long)h * 64 + i) * 64 + jg);
#pragma unroll
  for (int e = 0; e < 4; ++e) sin4[e] = ip[e];
  for (int cc = 0; cc < NCH; ++cc) {
    const long bhc = (long)bh * NCH + cc;
    f32x4* slp = (f32x4*)(SL + (bhc * 64 + i) * 64 + jg);
    const float Ai = AC[bhc * 64 + i];
    f32x4 sl4[4];
#pragma unroll
    for (int e = 0; e < 4; ++e) sl4[e] = slp[e];
#pragma unroll
    for (int e = 0; e < 4; ++e) slp[e] = sin4[e];          // S_in(c) for S2b
#pragma unroll
    for (int e = 0; e < 4; ++e) sin4[e] = Ai * sin4[e] + sl4[e];
  }
  f32x4* op = (f32x4*)(st1 + ((long)bh * 64 + i) * 64 + jg);
#pragma unroll
  for (int e = 0; e < 4; ++e) op[e] = sin4[e];
}

// ---------------- S2b: cross-chunk correction y += rtil @ S_in ----------------
__global__ __launch_bounds__(256) void scan_corr(
    const float* __restrict__ SL, const u16* __restrict__ rtil, float* __restrict__ ys) {
  __shared__ __align__(16) float S[64 * 64];
  const int bhc = blockIdx.x;
  const int c = bhc & (NCH - 1), h = (bhc >> 4) & (NH - 1), b = bhc >> 8;
  const int tid = threadIdx.x;
  const f32x4* sp = (const f32x4*)(SL + (long)bhc * 4096);
  for (int q = tid; q < 1024; q += 256) ((f32x4*)S)[q] = sp[q];
  __syncthreads();
  const int t = tid >> 2, jg = (tid & 3) * 16;
  const long base = ((long)(b * TTOK + c * CLEN + t) * DD) + h * HD;
  f32x4 yacc[4] = {};
  const u16* rp = rtil + base;
#pragma unroll 8
  for (int i = 0; i < 64; ++i) {
    const float r = b2f(rp[i]);
    const f32x4* srow = (const f32x4*)&S[i * 64 + jg];
#pragma unroll
    for (int e = 0; e < 4; ++e) yacc[e] += r * srow[e];
  }
  f32x4* yp = (f32x4*)(ys + base + jg);
#pragma unroll
  for (int e = 0; e < 4; ++e) yp[e] += yacc[e];
}

// ---------------- GroupNorm(hd=64) * SiLU(g) -> o (bf16) ----------------
__global__ __launch_bounds__(256) void ln_silu(
    const float* __restrict__ ys, const u16* __restrict__ gP,
    const float* __restrict__ lnw, const float* __restrict__ lnb,
    u16* __restrict__ oB) {
  const int ridx = blockIdx.x * 4 + (threadIdx.x >> 6);   // (token*16 + h)
  const int lane = threadIdx.x & 63;
  const long basem = (long)ridx * 64;
  const float y = ys[basem + lane];
  float su = y, sq = y * y;
#pragma unroll
  for (int msk = 1; msk < 64; msk <<= 1) {
    su += __shfl_xor(su, msk, 64);
    sq += __shfl_xor(sq, msk, 64);
  }
  const float mean = su * (1.f / 64.f);
  const float var = sq * (1.f / 64.f) - mean * mean;
  const float rs = rsqrtf(var + 1e-5f);
  const float g = b2f(gP[basem + lane]);
  const float silu = g / (1.f + expf(-g));
  const float val = silu * ((y - mean) * rs * lnw[lane] + lnb[lane]);
  oB[basem + lane] = f2b(val);
}

// ---------------- launcher ----------------
extern "C" void kernel_launch(void* const* d_in, const int* in_sizes, int n_in,
                              void* d_out, int out_size, void* d_ws, size_t ws_size,
                              hipStream_t stream) {
  const float* x   = (const float*)d_in[0];
  const float* xw  = (const float*)d_in[1];
  const float* rW  = (const float*)d_in[2];
  const float* kW  = (const float*)d_in[3];
  const float* vW  = (const float*)d_in[4];
  const float* gW  = (const float*)d_in[5];
  const float* r_la = (const float*)d_in[6],  *r_lb = (const float*)d_in[7],  *r_ll = (const float*)d_in[8];
  const float* k_la = (const float*)d_in[9],  *k_lb = (const float*)d_in[10], *k_ll = (const float*)d_in[11];
  const float* v_la = (const float*)d_in[12], *v_lb = (const float*)d_in[13], *v_ll = (const float*)d_in[14];
  const float* g_la = (const float*)d_in[15], *g_lb = (const float*)d_in[16], *g_ll = (const float*)d_in[17];
  const float* d_la = (const float*)d_in[18], *d_lb = (const float*)d_in[19], *d_ll = (const float*)d_in[20];
  const float* lnw = (const float*)d_in[21];
  const float* lnb = (const float*)d_in[22];
  const float* oW  = (const float*)d_in[23];
  const float* initS = (const float*)d_in[24];
  const float* uP  = (const float*)d_in[25];
  float* out = (float*)d_out;

  // workspace layout (~183 MB total)
  char* ws = (char*)d_ws;
  u16*   W_all  = (u16*)(ws + 0);                  // [5][1024][1024] bf16 (r,k,v,g,o)
  u16*   la_all = (u16*)(ws + 10485760);           // [5][64][1024]
  u16*   lb_all = (u16*)(ws + 11141120);           // [5][1024][64]
  float* ll_all = (float*)(ws + 11796480);         // [5][1024]
  u16*   lerpx  = (u16*)(ws + 11816960);           // [4096][1024] bf16
  float* dxP    = (float*)(ws + 20205568);         // [4096][1024] f32
  u16*   t1_all = (u16*)(ws + 36982784);           // [5][4096][64] bf16
  u16*   z_all  = (u16*)(ws + 39604224);           // [5][4096][1024] bf16
  u16*   rkvg   = (u16*)(ws + 81547264);           // [4][4096][1024] bf16
  float* wbuf   = (float*)(ws + 115101696);        // [4096][1024] f32
  u16*   rtil   = (u16*)(ws + 131878912);          // [4096][1024] bf16
  float* SL     = (float*)(ws + 140267520);        // [1024][64][64] f32
  float* AC     = (float*)(ws + 157044736);        // [1024][64] f32
  float* ys     = (float*)(ws + 157306880);        // [4096][1024] f32
  u16*   oB     = (u16*)(ws + 174084096);          // [4096][1024] bf16

  convW<<<5120, 256, 0, stream>>>(rW, kW, vW, gW, oW, W_all);
  convLora<<<645, 256, 0, stream>>>(r_la, k_la, v_la, g_la, d_la,
                                    r_lb, k_lb, v_lb, g_lb, d_lb,
                                    r_ll, k_ll, v_ll, g_ll, d_ll,
                                    la_all, lb_all, ll_all);
  prep<<<4096, 256, 0, stream>>>(x, xw, lerpx, dxP);

  // LoRA stage 1 (all 5): t1 = tanh(lerpx @ la^T)      [4096 x 64]
  gemm_bt<64, 64, 1><<<dim3(1, 64, 5), 256, 0, stream>>>(
      lerpx, 0L, la_all, 65536L, (void*)t1_all, 262144L, nullptr, nullptr, nullptr, MT, 64, 1024);
  // LoRA stage 2 (all 5): z = bf16(x + dx*(ll + t1 @ lb^T))   [4096 x 1024]
  gemm_bt<128, 128, 2><<<dim3(8, 32, 5), 256, 0, stream>>>(
      t1_all, 262144L, lb_all, 65536L, (void*)z_all, 4194304L, ll_all, x, dxP, MT, 1024, 64);
  // d-outer stage 1: t2 = tanh(z_d @ d_la^T)
  gemm_bt<64, 64, 1><<<dim3(1, 64, 1), 256, 0, stream>>>(
      z_all + 4L * 4194304, 0L, la_all + 4L * 65536, 0L, (void*)t1_all, 0L, nullptr, nullptr, nullptr, MT, 64, 1024);
  // d-outer stage 2: w = exp(-exp(d_ll + t2 @ d_lb^T))  (f32)
  gemm_bt<128, 128, 3><<<dim3(8, 32, 1), 256, 0, stream>>>(
      t1_all, 0L, lb_all + 4L * 65536, 0L, (void*)wbuf, 0L, ll_all + 4096, nullptr, nullptr, MT, 1024, 64);
  // projections r,k,v,g = z @ W^T (bf16 out)
  gemm_bt<128, 128, 4><<<dim3(8, 32, 4), 256, 0, stream>>>(
      z_all, 4194304L, W_all, 1048576L, (void*)rkvg, 4194304L, nullptr, nullptr, nullptr, MT, 1024, 1024);

  // chunked WKV scan
  scan_local<<<1024, 64, 0, stream>>>(rkvg, rkvg + 4194304L, rkvg + 2L * 4194304, wbuf,
                                      uP, ys, rtil, SL, AC);
  scan_prop<<<64, 256, 0, stream>>>(SL, AC, initS, out + 4194304);
  scan_corr<<<1024, 256, 0, stream>>>(SL, rtil, ys);

  // o = silu(g) * groupnorm(y); out = o @ oW^T
  ln_silu<<<16384, 256, 0, stream>>>(ys, rkvg + 3L * 4194304, lnw, lnb, oB);
  gemm_bt<128, 128, 0><<<dim3(8, 32, 1), 256, 0, stream>>>(
      oB, 0L, W_all + 4L * 1048576, 0L, (void*)out, 0L, nullptr, nullptr, nullptr, MT, 1024, 1024);
}

// Round 2
// 399.280 us; speedup vs baseline: 1.2234x; 1.2234x over previous
//
#include <hip/hip_runtime.h>
#include <hip/hip_bf16.h>

typedef unsigned short u16;
typedef unsigned int u32;
typedef __attribute__((ext_vector_type(4))) float f32x4;
typedef __attribute__((ext_vector_type(8))) short s16x8;

#define AS1 __attribute__((address_space(1)))
#define AS3 __attribute__((address_space(3)))

#define NB 4
#define TTOK 1024
#define DD 1024
#define NH 16
#define HD 64
#define MT 4096      // B*T tokens
#define NCH 16       // chunks per (b,h)
#define CLEN 64      // chunk length

static __device__ __forceinline__ float b2f(u16 u) {
  union { unsigned int u; float f; } c; c.u = ((unsigned int)u) << 16; return c.f;
}
static __device__ __forceinline__ u16 f2b(float f) {
  union { float f; unsigned int u; } c; c.f = f;
  return (u16)((c.u + 0x7fffu + ((c.u >> 16) & 1u)) >> 16);
}
static __device__ __forceinline__ float rdl(float v, int i) {
  union { float f; int s; } c; c.f = v;
  union { int s; float f; } o; o.s = __builtin_amdgcn_readlane(c.s, i);
  return o.f;
}
// direct global->LDS async copy, 16B per lane
static __device__ __forceinline__ void gload16(const u16* g, u16* l) {
  __builtin_amdgcn_global_load_lds((const AS1 u32*)g, (AS3 u32*)l, 16, 0, 0);
}
// LDS byte-offset swizzle: XOR bits 4..6 with row bits (row stride = 128B).
// Involution; keeps 16B chunks contiguous. Spreads the 16-lane same-col
// ds_read_b128 pattern to ~2-way bank aliasing (free).
static __device__ __forceinline__ int swz(int lin) {
  return lin ^ (((lin >> 9) & 3) << 5) ^ (((lin >> 7) & 1) << 4);
}

// ---------------- weight conversion / packing ----------------
__global__ __launch_bounds__(256) void convW(const float* __restrict__ s0, const float* __restrict__ s1,
                                             const float* __restrict__ s2, const float* __restrict__ s3,
                                             const float* __restrict__ s4, u16* __restrict__ dst) {
  long f = ((long)blockIdx.x * 256 + threadIdx.x) << 2;   // 5 * 1048576 elems
  int sel = (int)(f >> 20);
  const float* s = sel == 0 ? s0 : sel == 1 ? s1 : sel == 2 ? s2 : sel == 3 ? s3 : s4;
  long off = f & 1048575;
  f32x4 v = *(const f32x4*)&s[off];
  ushort4 o; o.x = f2b(v[0]); o.y = f2b(v[1]); o.z = f2b(v[2]); o.w = f2b(v[3]);
  *(ushort4*)&dst[f] = o;
}

__global__ __launch_bounds__(256) void convLora(
    const float* a0, const float* a1, const float* a2, const float* a3, const float* a4,
    const float* b0, const float* b1, const float* b2, const float* b3, const float* b4,
    const float* l0, const float* l1, const float* l2, const float* l3, const float* l4,
    u16* __restrict__ laD, u16* __restrict__ lbD, float* __restrict__ llD) {
  long f = ((long)blockIdx.x * 256 + threadIdx.x) << 2;
  if (f < 327680) {            // 5 x 65536 la
    int sel = (int)(f >> 16); long off = f & 65535;
    const float* s = sel == 0 ? a0 : sel == 1 ? a1 : sel == 2 ? a2 : sel == 3 ? a3 : a4;
    f32x4 v = *(const f32x4*)&s[off];
    ushort4 o; o.x = f2b(v[0]); o.y = f2b(v[1]); o.z = f2b(v[2]); o.w = f2b(v[3]);
    *(ushort4*)&laD[f] = o;
  } else if (f < 655360) {     // 5 x 65536 lb
    long g = f - 327680;
    int sel = (int)(g >> 16); long off = g & 65535;
    const float* s = sel == 0 ? b0 : sel == 1 ? b1 : sel == 2 ? b2 : sel == 3 ? b3 : b4;
    f32x4 v = *(const f32x4*)&s[off];
    ushort4 o; o.x = f2b(v[0]); o.y = f2b(v[1]); o.z = f2b(v[2]); o.w = f2b(v[3]);
    *(ushort4*)&lbD[g] = o;
  } else if (f < 660480) {     // 5 x 1024 ll (f32 copy)
    long g = f - 655360;
    int sel = (int)(g >> 10); long off = g & 1023;
    const float* s = sel == 0 ? l0 : sel == 1 ? l1 : sel == 2 ? l2 : sel == 3 ? l3 : l4;
    *(f32x4*)&llD[g] = *(const f32x4*)&s[off];
  }
}

// ---------------- token shift prep: dx (f32), lerpx (bf16) ----------------
__global__ __launch_bounds__(256) void prep(const float* __restrict__ x, const float* __restrict__ xw,
                                            u16* __restrict__ lerpx, float* __restrict__ dxP) {
  long f = ((long)blockIdx.x * 256 + threadIdx.x) << 2;
  int d = (int)(f & (DD - 1));
  int m = (int)(f >> 10);
  int t = m & (TTOK - 1);
  f32x4 xv = *(const f32x4*)&x[f];
  f32x4 xm = {};
  if (t > 0) xm = *(const f32x4*)&x[f - DD];
  f32x4 xwv = *(const f32x4*)&xw[d];
  f32x4 dx = xm - xv;
  f32x4 lp = xv + dx * xwv;
  *(f32x4*)&dxP[f] = dx;
  ushort4 o; o.x = f2b(lp[0]); o.y = f2b(lp[1]); o.z = f2b(lp[2]); o.w = f2b(lp[3]);
  *(ushort4*)&lerpx[f] = o;
}

// ---------------- bf16 MFMA GEMM, m97-style: BK=64, global_load_lds, swizzled LDS ----
// C[m][n] = sum_k A[m][k]*B[n][k].  K % 64 == 0, M % BM == 0, N % BN == 0.
// EPI: 0 = store f32; 1 = store bf16(tanh); 2 = z-epilogue bf16(x + dx*(ll+acc));
//      3 = store f32 exp(-exp(ll+acc)); 4 = store bf16
template<int BM, int BN, int EPI>
__launch_bounds__(256)
__global__ void gemm2(const u16* __restrict__ Ab, long sAz,
                      const u16* __restrict__ Bb, long sBz,
                      void* __restrict__ Ob, long sOz,
                      const float* __restrict__ llb,
                      const float* __restrict__ xP,
                      const float* __restrict__ dxP,
                      int M, int N, int K) {
  __shared__ __align__(16) u16 As[BM * 64];
  __shared__ __align__(16) u16 Bs[BN * 64];
  const int z = blockIdx.z;
  const u16* A = Ab + (long)z * sAz;
  const u16* Bw = Bb + (long)z * sBz;
  const int m0 = blockIdx.y * BM;
  const int n0 = blockIdx.x * BN;
  const int tid = threadIdx.x;
  const int l = tid & 63;
  const int wv = tid >> 6;
  constexpr int WM = BM / 2, WN = BN / 2;
  constexpr int FM = WM / 16, FN = WN / 16;
  const int wm0 = (wv >> 1) * WM, wn0 = (wv & 1) * WN;
  const int lrow = l & 15, lk = (l >> 4) * 8;
  constexpr int GA = BM / 32, GB = BN / 32;   // 16B gloads per thread per tile
  // staging: LDS dest is linear (lane-contiguous); global source is inverse-swizzled
  int gA[GA], gB[GB];
#pragma unroll
  for (int q = 0; q < GA; ++q) {
    int d = (q * 256 + tid) * 16;
    int bb = swz(d);
    gA[q] = (m0 + (bb >> 7)) * K + ((bb & 127) >> 1);
  }
#pragma unroll
  for (int q = 0; q < GB; ++q) {
    int d = (q * 256 + tid) * 16;
    int bb = swz(d);
    gB[q] = (n0 + (bb >> 7)) * K + ((bb & 127) >> 1);
  }
  // fragment ds_read byte offsets (swizzled), fixed per thread
  int aOff[FM][2], bOff[FN][2];
#pragma unroll
  for (int m = 0; m < FM; ++m)
#pragma unroll
    for (int kk = 0; kk < 2; ++kk)
      aOff[m][kk] = swz(((wm0 + m * 16 + lrow) << 7) + (kk << 6) + (lk << 1));
#pragma unroll
  for (int n = 0; n < FN; ++n)
#pragma unroll
    for (int kk = 0; kk < 2; ++kk)
      bOff[n][kk] = swz(((wn0 + n * 16 + lrow) << 7) + (kk << 6) + (lk << 1));
  f32x4 acc[FM][FN] = {};
  for (int k0 = 0; k0 < K; k0 += 64) {
    __syncthreads();
#pragma unroll
    for (int q = 0; q < GA; ++q)
      gload16(&A[(long)gA[q] + k0], (u16*)((char*)As + (q * 256 + tid) * 16));
#pragma unroll
    for (int q = 0; q < GB; ++q)
      gload16(&Bw[(long)gB[q] + k0], (u16*)((char*)Bs + (q * 256 + tid) * 16));
    __syncthreads();   // drains vmcnt -> LDS tile complete
#pragma unroll
    for (int kk = 0; kk < 2; ++kk) {
      s16x8 af[FM], bfr[FN];
#pragma unroll
      for (int m = 0; m < FM; ++m) af[m] = *(const s16x8*)((const char*)As + aOff[m][kk]);
#pragma unroll
      for (int n = 0; n < FN; ++n) bfr[n] = *(const s16x8*)((const char*)Bs + bOff[n][kk]);
#pragma unroll
      for (int m = 0; m < FM; ++m)
#pragma unroll
        for (int n = 0; n < FN; ++n)
          acc[m][n] = __builtin_amdgcn_mfma_f32_16x16x32_bf16(af[m], bfr[n], acc[m][n], 0, 0, 0);
    }
  }
#pragma unroll
  for (int m = 0; m < FM; ++m) {
#pragma unroll
    for (int n = 0; n < FN; ++n) {
      const int j = n0 + wn0 + n * 16 + lrow;
#pragma unroll
      for (int q = 0; q < 4; ++q) {
        const int i = m0 + wm0 + m * 16 + (l >> 4) * 4 + q;
        const long off = (long)i * N + j;
        float v = acc[m][n][q];
        if constexpr (EPI == 0) {
          ((float*)Ob + (long)z * sOz)[off] = v;
        } else if constexpr (EPI == 1) {
          ((u16*)Ob + (long)z * sOz)[off] = f2b(tanhf(v));
        } else if constexpr (EPI == 2) {
          float val = xP[off] + dxP[off] * (llb[(long)z * N + j] + v);
          ((u16*)Ob + (long)z * sOz)[off] = f2b(val);
        } else if constexpr (EPI == 3) {
          ((float*)Ob + (long)z * sOz)[off] = expf(-expf(llb[j] + v));
        } else {
          ((u16*)Ob + (long)z * sOz)[off] = f2b(v);
        }
      }
    }
  }
}

// ---------------- S1: chunk-local WKV scan (S0 = 0), 2 waves/block, i-split ----------
__global__ __launch_bounds__(128) void scan_local(
    const u16* __restrict__ rP, const u16* __restrict__ kP,
    const u16* __restrict__ vP, const float* __restrict__ wP,
    const float* __restrict__ uP, float* __restrict__ ys0, float* __restrict__ ys1,
    u16* __restrict__ rtil, float* __restrict__ SL, float* __restrict__ AC) {
  const int bhc = blockIdx.x;
  const int c = bhc & (NCH - 1), h = (bhc >> 4) & (NH - 1), b = bhc >> 8;
  const int j = threadIdx.x & 63;
  const int h2 = threadIdx.x >> 6;       // 0: state rows 0..31, 1: rows 32..63
  float s[32];
#pragma unroll
  for (int x = 0; x < 32; ++x) s[x] = 0.f;
  float Aj = 1.f;
  const float uj = uP[h * HD + j];
  long base = ((long)(b * TTOK + c * CLEN) << 10) + h * HD;
  float rj = b2f(rP[base + j]), kj = b2f(kP[base + j]);
  float vj = b2f(vP[base + j]), wj = wP[base + j];
  for (int tt = 0; tt < CLEN; ++tt) {
    const long nbase = base + DD;
    float rn = 0.f, kn = 0.f, vn = 0.f, wn = 0.f;
    if (tt + 1 < CLEN) {      // prefetch next step
      rn = b2f(rP[nbase + j]); kn = b2f(kP[nbase + j]);
      vn = b2f(vP[nbase + j]); wn = wP[nbase + j];
    }
    float ya = 0.f, yb = 0.f;
    if (h2 == 0) {
      rtil[base + j] = f2b(rj * Aj);     // r_t * A_{t-1}
#pragma unroll
      for (int x = 0; x < 32; x += 2) {
        { const float ri = rdl(rj, x), ki = rdl(kj, x), wi = rdl(wj, x);
          ya = fmaf(ri, s[x], ya); s[x] = fmaf(wi, s[x], ki * vj); }
        { const float ri = rdl(rj, x + 1), ki = rdl(kj, x + 1), wi = rdl(wj, x + 1);
          yb = fmaf(ri, s[x + 1], yb); s[x + 1] = fmaf(wi, s[x + 1], ki * vj); }
      }
      ys0[base + j] = ya + yb;
    } else {
      // u-term: y += (sum_i r_i u_i k_i) * v_j   (wave-reduce, replaces per-i u work)
      float al = rj * uj * kj;
#pragma unroll
      for (int msk = 1; msk < 64; msk <<= 1) al += __shfl_xor(al, msk, 64);
      ya = al * vj;
#pragma unroll
      for (int x = 0; x < 32; x += 2) {
        { const float ri = rdl(rj, 32 + x), ki = rdl(kj, 32 + x), wi = rdl(wj, 32 + x);
          ya = fmaf(ri, s[x], ya); s[x] = fmaf(wi, s[x], ki * vj); }
        { const float ri = rdl(rj, 33 + x), ki = rdl(kj, 33 + x), wi = rdl(wj, 33 + x);
          yb = fmaf(ri, s[x + 1], yb); s[x + 1] = fmaf(wi, s[x + 1], ki * vj); }
      }
      ys1[base + j] = ya + yb;
    }
    Aj *= wj;
    base = nbase;
    rj = rn; kj = kn; vj = vn; wj = wn;
  }
#pragma unroll
  for (int x = 0; x < 32; ++x)
    SL[((long)bhc * 64 + h2 * 32 + x) * 64 + j] = s[x];
  if (h2 == 0) AC[(long)bhc * 64 + j] = Aj;
}

// ---------------- S2a: propagate chunk-boundary states; overwrite SL[c] with S_in(c) ----------------
__global__ __launch_bounds__(256) void scan_prop(
    float* __restrict__ SL, const float* __restrict__ AC,
    const float* __restrict__ initS, float* __restrict__ st1) {
  const int bh = blockIdx.x;          // b*16 + h
  const int h = bh & (NH - 1);
  const int tid = threadIdx.x;
  const int i = tid >> 2, jg = (tid & 3) * 16;
  f32x4 sin4[4];
  const f32x4* ip = (const f32x4*)(initS + ((long)h * 64 + i) * 64 + jg);
#pragma unroll
  for (int e = 0; e < 4; ++e) sin4[e] = ip[e];
  for (int cc = 0; cc < NCH; ++cc) {
    const long bhc = (long)bh * NCH + cc;
    f32x4* slp = (f32x4*)(SL + (bhc * 64 + i) * 64 + jg);
    const float Ai = AC[bhc * 64 + i];
    f32x4 sl4[4];
#pragma unroll
    for (int e = 0; e < 4; ++e) sl4[e] = slp[e];
#pragma unroll
    for (int e = 0; e < 4; ++e) slp[e] = sin4[e];          // S_in(c) for S2b
#pragma unroll
    for (int e = 0; e < 4; ++e) sin4[e] = Ai * sin4[e] + sl4[e];
  }
  f32x4* op = (f32x4*)(st1 + ((long)bh * 64 + i) * 64 + jg);
#pragma unroll
  for (int e = 0; e < 4; ++e) op[e] = sin4[e];
}

// ---------------- S2b: cross-chunk correction y += rtil @ S_in ----------------
__global__ __launch_bounds__(256) void scan_corr(
    const float* __restrict__ SL, const u16* __restrict__ rtil, float* __restrict__ ys) {
  __shared__ __align__(16) float S[64 * 64];
  const int bhc = blockIdx.x;
  const int c = bhc & (NCH - 1), h = (bhc >> 4) & (NH - 1), b = bhc >> 8;
  const int tid = threadIdx.x;
  const f32x4* sp = (const f32x4*)(SL + (long)bhc * 4096);
  for (int q = tid; q < 1024; q += 256) ((f32x4*)S)[q] = sp[q];
  __syncthreads();
  const int t = tid >> 2, jg = (tid & 3) * 16;
  const long base = ((long)(b * TTOK + c * CLEN + t) * DD) + h * HD;
  f32x4 yacc[4] = {};
  const u16* rp = rtil + base;
#pragma unroll 8
  for (int i = 0; i < 64; ++i) {
    const float r = b2f(rp[i]);
    const f32x4* srow = (const f32x4*)&S[i * 64 + jg];
#pragma unroll
    for (int e = 0; e < 4; ++e) yacc[e] += r * srow[e];
  }
  f32x4* yp = (f32x4*)(ys + base + jg);
#pragma unroll
  for (int e = 0; e < 4; ++e) yp[e] += yacc[e];
}

// ---------------- GroupNorm(hd=64) * SiLU(g) -> o (bf16) ----------------
__global__ __launch_bounds__(256) void ln_silu(
    const float* __restrict__ ys0, const float* __restrict__ ys1,
    const u16* __restrict__ gP,
    const float* __restrict__ lnw, const float* __restrict__ lnb,
    u16* __restrict__ oB) {
  const int ridx = blockIdx.x * 4 + (threadIdx.x >> 6);   // (token*16 + h)
  const int lane = threadIdx.x & 63;
  const long basem = (long)ridx * 64;
  const float y = ys0[basem + lane] + ys1[basem + lane];
  float su = y, sq = y * y;
#pragma unroll
  for (int msk = 1; msk < 64; msk <<= 1) {
    su += __shfl_xor(su, msk, 64);
    sq += __shfl_xor(sq, msk, 64);
  }
  const float mean = su * (1.f / 64.f);
  const float var = sq * (1.f / 64.f) - mean * mean;
  const float rs = rsqrtf(var + 1e-5f);
  const float g = b2f(gP[basem + lane]);
  const float silu = g / (1.f + expf(-g));
  const float val = silu * ((y - mean) * rs * lnw[lane] + lnb[lane]);
  oB[basem + lane] = f2b(val);
}

// ---------------- launcher ----------------
extern "C" void kernel_launch(void* const* d_in, const int* in_sizes, int n_in,
                              void* d_out, int out_size, void* d_ws, size_t ws_size,
                              hipStream_t stream) {
  const float* x   = (const float*)d_in[0];
  const float* xw  = (const float*)d_in[1];
  const float* rW  = (const float*)d_in[2];
  const float* kW  = (const float*)d_in[3];
  const float* vW  = (const float*)d_in[4];
  const float* gW  = (const float*)d_in[5];
  const float* r_la = (const float*)d_in[6],  *r_lb = (const float*)d_in[7],  *r_ll = (const float*)d_in[8];
  const float* k_la = (const float*)d_in[9],  *k_lb = (const float*)d_in[10], *k_ll = (const float*)d_in[11];
  const float* v_la = (const float*)d_in[12], *v_lb = (const float*)d_in[13], *v_ll = (const float*)d_in[14];
  const float* g_la = (const float*)d_in[15], *g_lb = (const float*)d_in[16], *g_ll = (const float*)d_in[17];
  const float* d_la = (const float*)d_in[18], *d_lb = (const float*)d_in[19], *d_ll = (const float*)d_in[20];
  const float* lnw = (const float*)d_in[21];
  const float* lnb = (const float*)d_in[22];
  const float* oW  = (const float*)d_in[23];
  const float* initS = (const float*)d_in[24];
  const float* uP  = (const float*)d_in[25];
  float* out = (float*)d_out;

  // workspace layout (~183 MB total; ys1 overlays dead dxP region)
  char* ws = (char*)d_ws;
  u16*   W_all  = (u16*)(ws + 0);                  // [5][1024][1024] bf16 (r,k,v,g,o)
  u16*   la_all = (u16*)(ws + 10485760);           // [5][64][1024]
  u16*   lb_all = (u16*)(ws + 11141120);           // [5][1024][64]
  float* ll_all = (float*)(ws + 11796480);         // [5][1024]
  u16*   lerpx  = (u16*)(ws + 11816960);           // [4096][1024] bf16
  float* dxP    = (float*)(ws + 20205568);         // [4096][1024] f32   (dead after z-stage2)
  float* ys1    = (float*)(ws + 20205568);         // [4096][1024] f32   (overlay)
  u16*   t1_all = (u16*)(ws + 36982784);           // [5][4096][64] bf16
  u16*   z_all  = (u16*)(ws + 39604224);           // [5][4096][1024] bf16
  u16*   rkvg   = (u16*)(ws + 81547264);           // [4][4096][1024] bf16
  float* wbuf   = (float*)(ws + 115101696);        // [4096][1024] f32
  u16*   rtil   = (u16*)(ws + 131878912);          // [4096][1024] bf16
  float* SL     = (float*)(ws + 140267520);        // [1024][64][64] f32
  float* AC     = (float*)(ws + 157044736);        // [1024][64] f32
  float* ys     = (float*)(ws + 157306880);        // [4096][1024] f32
  u16*   oB     = (u16*)(ws + 174084096);          // [4096][1024] bf16

  convW<<<5120, 256, 0, stream>>>(rW, kW, vW, gW, oW, W_all);
  convLora<<<645, 256, 0, stream>>>(r_la, k_la, v_la, g_la, d_la,
                                    r_lb, k_lb, v_lb, g_lb, d_lb,
                                    r_ll, k_ll, v_ll, g_ll, d_ll,
                                    la_all, lb_all, ll_all);
  prep<<<4096, 256, 0, stream>>>(x, xw, lerpx, dxP);

  // LoRA stage 1 (all 5): t1 = tanh(lerpx @ la^T)      [4096 x 64]
  gemm2<64, 64, 1><<<dim3(1, 64, 5), 256, 0, stream>>>(
      lerpx, 0L, la_all, 65536L, (void*)t1_all, 262144L, nullptr, nullptr, nullptr, MT, 64, 1024);
  // LoRA stage 2 (all 5): z = bf16(x + dx*(ll + t1 @ lb^T))   [4096 x 1024]
  gemm2<128, 128, 2><<<dim3(8, 32, 5), 256, 0, stream>>>(
      t1_all, 262144L, lb_all, 65536L, (void*)z_all, 4194304L, ll_all, x, dxP, MT, 1024, 64);
  // d-outer stage 1: t2 = tanh(z_d @ d_la^T)
  gemm2<64, 64, 1><<<dim3(1, 64, 1), 256, 0, stream>>>(
      z_all + 4L * 4194304, 0L, la_all + 4L * 65536, 0L, (void*)t1_all, 0L, nullptr, nullptr, nullptr, MT, 64, 1024);
  // d-outer stage 2: w = exp(-exp(d_ll + t2 @ d_lb^T))  (f32)
  gemm2<128, 128, 3><<<dim3(8, 32, 1), 256, 0, stream>>>(
      t1_all, 0L, lb_all + 4L * 65536, 0L, (void*)wbuf, 0L, ll_all + 4096, nullptr, nullptr, MT, 1024, 64);
  // projections r,k,v,g = z @ W^T (bf16 out)
  gemm2<128, 128, 4><<<dim3(8, 32, 4), 256, 0, stream>>>(
      z_all, 4194304L, W_all, 1048576L, (void*)rkvg, 4194304L, nullptr, nullptr, nullptr, MT, 1024, 1024);

  // chunked WKV scan
  scan_local<<<1024, 128, 0, stream>>>(rkvg, rkvg + 4194304L, rkvg + 2L * 4194304, wbuf,
                                       uP, ys, ys1, rtil, SL, AC);
  scan_prop<<<64, 256, 0, stream>>>(SL, AC, initS, out + 4194304);
  scan_corr<<<1024, 256, 0, stream>>>(SL, rtil, ys);

  // o = silu(g) * groupnorm(y); out = o @ oW^T
  ln_silu<<<16384, 256, 0, stream>>>(ys, ys1, rkvg + 3L * 4194304, lnw, lnb, oB);
  gemm2<128, 128, 0><<<dim3(8, 32, 1), 256, 0, stream>>>(
      oB, 0L, W_all + 4L * 1048576, 0L, (void*)out, 0L, nullptr, nullptr, nullptr, MT, 1024, 1024);
}

// Round 3
// 388.406 us; speedup vs baseline: 1.2577x; 1.0280x over previous
//
#include <hip/hip_runtime.h>
#include <hip/hip_bf16.h>

typedef unsigned short u16;
typedef unsigned int u32;
typedef __attribute__((ext_vector_type(4))) float f32x4;
typedef __attribute__((ext_vector_type(8))) short s16x8;

#define AS1 __attribute__((address_space(1)))
#define AS3 __attribute__((address_space(3)))

#define NB 4
#define TTOK 1024
#define DD 1024
#define NH 16
#define HD 64
#define MT 4096      // B*T tokens
#define NCH 16       // chunks per (b,h)
#define CLEN 64      // chunk length

static __device__ __forceinline__ float b2f(u16 u) {
  union { unsigned int u; float f; } c; c.u = ((unsigned int)u) << 16; return c.f;
}
static __device__ __forceinline__ float ubit(u32 u) {
  union { u32 u; float f; } c; c.u = u; return c.f;
}
static __device__ __forceinline__ u16 f2b(float f) {
  union { float f; unsigned int u; } c; c.f = f;
  return (u16)((c.u + 0x7fffu + ((c.u >> 16) & 1u)) >> 16);
}
// direct global->LDS async copy, 16B per lane
static __device__ __forceinline__ void gload16(const u16* g, u16* l) {
  __builtin_amdgcn_global_load_lds((const AS1 u32*)g, (AS3 u32*)l, 16, 0, 0);
}
// LDS byte-offset swizzle (involution, keeps 16B chunks intact)
static __device__ __forceinline__ int swz(int lin) {
  return lin ^ (((lin >> 9) & 3) << 5) ^ (((lin >> 7) & 1) << 4);
}

// ---------------- weight conversion / packing ----------------
__global__ __launch_bounds__(256) void convW(const float* __restrict__ s0, const float* __restrict__ s1,
                                             const float* __restrict__ s2, const float* __restrict__ s3,
                                             const float* __restrict__ s4, u16* __restrict__ dst) {
  long f = ((long)blockIdx.x * 256 + threadIdx.x) << 2;   // 5 * 1048576 elems
  int sel = (int)(f >> 20);
  const float* s = sel == 0 ? s0 : sel == 1 ? s1 : sel == 2 ? s2 : sel == 3 ? s3 : s4;
  long off = f & 1048575;
  f32x4 v = *(const f32x4*)&s[off];
  ushort4 o; o.x = f2b(v[0]); o.y = f2b(v[1]); o.z = f2b(v[2]); o.w = f2b(v[3]);
  *(ushort4*)&dst[f] = o;
}

__global__ __launch_bounds__(256) void convLora(
    const float* a0, const float* a1, const float* a2, const float* a3, const float* a4,
    const float* b0, const float* b1, const float* b2, const float* b3, const float* b4,
    const float* l0, const float* l1, const float* l2, const float* l3, const float* l4,
    u16* __restrict__ laD, u16* __restrict__ lbD, float* __restrict__ llD) {
  long f = ((long)blockIdx.x * 256 + threadIdx.x) << 2;
  if (f < 327680) {            // 5 x 65536 la
    int sel = (int)(f >> 16); long off = f & 65535;
    const float* s = sel == 0 ? a0 : sel == 1 ? a1 : sel == 2 ? a2 : sel == 3 ? a3 : a4;
    f32x4 v = *(const f32x4*)&s[off];
    ushort4 o; o.x = f2b(v[0]); o.y = f2b(v[1]); o.z = f2b(v[2]); o.w = f2b(v[3]);
    *(ushort4*)&laD[f] = o;
  } else if (f < 655360) {     // 5 x 65536 lb
    long g = f - 327680;
    int sel = (int)(g >> 16); long off = g & 65535;
    const float* s = sel == 0 ? b0 : sel == 1 ? b1 : sel == 2 ? b2 : sel == 3 ? b3 : b4;
    f32x4 v = *(const f32x4*)&s[off];
    ushort4 o; o.x = f2b(v[0]); o.y = f2b(v[1]); o.z = f2b(v[2]); o.w = f2b(v[3]);
    *(ushort4*)&lbD[g] = o;
  } else if (f < 660480) {     // 5 x 1024 ll (f32 copy)
    long g = f - 655360;
    int sel = (int)(g >> 10); long off = g & 1023;
    const float* s = sel == 0 ? l0 : sel == 1 ? l1 : sel == 2 ? l2 : sel == 3 ? l3 : l4;
    *(f32x4*)&llD[g] = *(const f32x4*)&s[off];
  }
}

// ---------------- token shift prep: lerpx, xB, dxB (all bf16) ----------------
__global__ __launch_bounds__(256) void prep(const float* __restrict__ x, const float* __restrict__ xw,
                                            u16* __restrict__ lerpx, u16* __restrict__ xB,
                                            u16* __restrict__ dxB) {
  long f = ((long)blockIdx.x * 256 + threadIdx.x) << 2;
  int d = (int)(f & (DD - 1));
  int m = (int)(f >> 10);
  int t = m & (TTOK - 1);
  f32x4 xv = *(const f32x4*)&x[f];
  f32x4 xm = {};
  if (t > 0) xm = *(const f32x4*)&x[f - DD];
  f32x4 xwv = *(const f32x4*)&xw[d];
  f32x4 dx = xm - xv;
  f32x4 lp = xv + dx * xwv;
  ushort4 o; o.x = f2b(lp[0]); o.y = f2b(lp[1]); o.z = f2b(lp[2]); o.w = f2b(lp[3]);
  *(ushort4*)&lerpx[f] = o;
  ushort4 ox; ox.x = f2b(xv[0]); ox.y = f2b(xv[1]); ox.z = f2b(xv[2]); ox.w = f2b(xv[3]);
  *(ushort4*)&xB[f] = ox;
  ushort4 od; od.x = f2b(dx[0]); od.y = f2b(dx[1]); od.z = f2b(dx[2]); od.w = f2b(dx[3]);
  *(ushort4*)&dxB[f] = od;
}

// ---------------- bf16 MFMA GEMM, m97-style: BK=64, global_load_lds, swizzled LDS ----
// C[m][n] = sum_k A[m][k]*B[n][k].
// EPI: 0 = store f32; 1 = store bf16(tanh); 2 = z-epilogue bf16(x + dx*(ll+acc));
//      3 = store f32 exp(-exp(ll+acc)); 4 = store bf16
template<int BM, int BN, int EPI>
__launch_bounds__(256)
__global__ void gemm2(const u16* __restrict__ Ab, long sAz,
                      const u16* __restrict__ Bb, long sBz,
                      void* __restrict__ Ob, long sOz,
                      const float* __restrict__ llb,
                      const u16* __restrict__ xB,
                      const u16* __restrict__ dxB,
                      int M, int N, int K) {
  __shared__ __align__(16) u16 As[BM * 64];
  __shared__ __align__(16) u16 Bs[BN * 64];
  const int z = blockIdx.z;
  const u16* A = Ab + (long)z * sAz;
  const u16* Bw = Bb + (long)z * sBz;
  const int m0 = blockIdx.y * BM;
  const int n0 = blockIdx.x * BN;
  const int tid = threadIdx.x;
  const int l = tid & 63;
  const int wv = tid >> 6;
  constexpr int WM = BM / 2, WN = BN / 2;
  constexpr int FM = WM / 16, FN = WN / 16;
  const int wm0 = (wv >> 1) * WM, wn0 = (wv & 1) * WN;
  const int lrow = l & 15, lk = (l >> 4) * 8;
  constexpr int GA = BM / 32, GB = BN / 32;   // 16B gloads per thread per tile
  int gA[GA], gB[GB];
#pragma unroll
  for (int q = 0; q < GA; ++q) {
    int d = (q * 256 + tid) * 16;
    int bb = swz(d);
    gA[q] = (m0 + (bb >> 7)) * K + ((bb & 127) >> 1);
  }
#pragma unroll
  for (int q = 0; q < GB; ++q) {
    int d = (q * 256 + tid) * 16;
    int bb = swz(d);
    gB[q] = (n0 + (bb >> 7)) * K + ((bb & 127) >> 1);
  }
  int aOff[FM][2], bOff[FN][2];
#pragma unroll
  for (int m = 0; m < FM; ++m)
#pragma unroll
    for (int kk = 0; kk < 2; ++kk)
      aOff[m][kk] = swz(((wm0 + m * 16 + lrow) << 7) + (kk << 6) + (lk << 1));
#pragma unroll
  for (int n = 0; n < FN; ++n)
#pragma unroll
    for (int kk = 0; kk < 2; ++kk)
      bOff[n][kk] = swz(((wn0 + n * 16 + lrow) << 7) + (kk << 6) + (lk << 1));
  f32x4 acc[FM][FN] = {};
  for (int k0 = 0; k0 < K; k0 += 64) {
    __syncthreads();
#pragma unroll
    for (int q = 0; q < GA; ++q)
      gload16(&A[(long)gA[q] + k0], (u16*)((char*)As + (q * 256 + tid) * 16));
#pragma unroll
    for (int q = 0; q < GB; ++q)
      gload16(&Bw[(long)gB[q] + k0], (u16*)((char*)Bs + (q * 256 + tid) * 16));
    __syncthreads();   // drains vmcnt -> LDS tile complete
#pragma unroll
    for (int kk = 0; kk < 2; ++kk) {
      s16x8 af[FM], bfr[FN];
#pragma unroll
      for (int m = 0; m < FM; ++m) af[m] = *(const s16x8*)((const char*)As + aOff[m][kk]);
#pragma unroll
      for (int n = 0; n < FN; ++n) bfr[n] = *(const s16x8*)((const char*)Bs + bOff[n][kk]);
#pragma unroll
      for (int m = 0; m < FM; ++m)
#pragma unroll
        for (int n = 0; n < FN; ++n)
          acc[m][n] = __builtin_amdgcn_mfma_f32_16x16x32_bf16(af[m], bfr[n], acc[m][n], 0, 0, 0);
    }
  }
#pragma unroll
  for (int m = 0; m < FM; ++m) {
#pragma unroll
    for (int n = 0; n < FN; ++n) {
      const int j = n0 + wn0 + n * 16 + lrow;
#pragma unroll
      for (int q = 0; q < 4; ++q) {
        const int i = m0 + wm0 + m * 16 + (l >> 4) * 4 + q;
        const long off = (long)i * N + j;
        float v = acc[m][n][q];
        if constexpr (EPI == 0) {
          ((float*)Ob + (long)z * sOz)[off] = v;
        } else if constexpr (EPI == 1) {
          ((u16*)Ob + (long)z * sOz)[off] = f2b(tanhf(v));
        } else if constexpr (EPI == 2) {
          float val = b2f(xB[off]) + b2f(dxB[off]) * (llb[(long)z * N + j] + v);
          ((u16*)Ob + (long)z * sOz)[off] = f2b(val);
        } else if constexpr (EPI == 3) {
          ((float*)Ob + (long)z * sOz)[off] = expf(-expf(llb[j] + v));
        } else {
          ((u16*)Ob + (long)z * sOz)[off] = f2b(v);
        }
      }
    }
  }
}

// ---------------- S1: chunk-local WKV scan, 4 waves/block, scalar-path broadcasts ----
// Wave q owns state rows i in [16q, 16q+16); r/k/w for those i come in via
// SMEM scalar loads (wave-uniform addresses forced with readfirstlane) and are
// unpacked with SALU ops -> inner loop is 3 VALU ops per (i,t).
__global__ __launch_bounds__(256) void scan_local(
    const u16* __restrict__ rP, const u16* __restrict__ kP,
    const u16* __restrict__ vP, const float* __restrict__ wP,
    const float* __restrict__ uP,
    float* __restrict__ ys0, float* __restrict__ ys1,
    float* __restrict__ ys2, float* __restrict__ ys3,
    u16* __restrict__ rtil, float* __restrict__ SL, float* __restrict__ AC) {
  const int bhc = blockIdx.x;
  const int c = bhc & (NCH - 1), h = (bhc >> 4) & (NH - 1), b = bhc >> 8;
  const int j = threadIdx.x & 63;
  const int qu = __builtin_amdgcn_readfirstlane(threadIdx.x >> 6);  // wave id, SGPR
  const int so = qu * 16;
  float s[16];
#pragma unroll
  for (int x = 0; x < 16; ++x) s[x] = 0.f;
  long base = ((long)(b * TTOK + c * CLEN) << 10) + h * HD;
  float* __restrict__ ysel = qu == 0 ? ys0 : qu == 1 ? ys1 : qu == 2 ? ys2 : ys3;

  // current-step scalar r/k (packed u32 pairs) and w (f32)
  u32 rc[8], kc[8]; float wc[16];
#pragma unroll
  for (int e = 0; e < 8; ++e) {
    rc[e] = *(const u32*)(rP + base + so + 2 * e);
    kc[e] = *(const u32*)(kP + base + so + 2 * e);
  }
#pragma unroll
  for (int e = 0; e < 16; ++e) wc[e] = wP[base + so + e];

  float Aj = 1.f;
  const float uj = uP[h * HD + j];
  float vjc = b2f(vP[base + j]);
  float rjv = 0.f, kjv = 0.f, wjv = 0.f;
  if (qu == 0) { rjv = b2f(rP[base + j]); kjv = b2f(kP[base + j]); wjv = wP[base + j]; }

  for (int tt = 0; tt < CLEN; ++tt) {
    const long nb = base + DD;
    // prefetch next step (unguarded: last-step reads stay inside workspace)
    u32 rn_[8], kn_[8]; float wn_[16];
#pragma unroll
    for (int e = 0; e < 8; ++e) {
      rn_[e] = *(const u32*)(rP + nb + so + 2 * e);
      kn_[e] = *(const u32*)(kP + nb + so + 2 * e);
    }
#pragma unroll
    for (int e = 0; e < 16; ++e) wn_[e] = wP[nb + so + e];
    float vjn = b2f(vP[nb + j]);
    float rjn = 0.f, kjn = 0.f, wjn = 0.f;
    if (qu == 0) { rjn = b2f(rP[nb + j]); kjn = b2f(kP[nb + j]); wjn = wP[nb + j]; }

    float ya = 0.f, yb = 0.f;
#pragma unroll
    for (int e = 0; e < 8; ++e) {
      const float r0 = ubit(rc[e] << 16), r1 = ubit(rc[e] & 0xffff0000u);
      const float k0 = ubit(kc[e] << 16), k1 = ubit(kc[e] & 0xffff0000u);
      ya = fmaf(r0, s[2 * e], ya);
      s[2 * e] = fmaf(wc[2 * e], s[2 * e], k0 * vjc);
      yb = fmaf(r1, s[2 * e + 1], yb);
      s[2 * e + 1] = fmaf(wc[2 * e + 1], s[2 * e + 1], k1 * vjc);
    }
    float y = ya + yb;
    if (qu == 0) {
      rtil[base + j] = f2b(rjv * Aj);      // r_t * A_{t-1}
      float al = rjv * uj * kjv;           // u-term: (sum_i r_i u_i k_i) * v_j
#pragma unroll
      for (int msk = 1; msk < 64; msk <<= 1) al += __shfl_xor(al, msk, 64);
      y = fmaf(al, vjc, y);
      Aj *= wjv;
      rjv = rjn; kjv = kjn; wjv = wjn;
    }
    ysel[base + j] = y;
    base = nb; vjc = vjn;
#pragma unroll
    for (int e = 0; e < 8; ++e) { rc[e] = rn_[e]; kc[e] = kn_[e]; }
#pragma unroll
    for (int e = 0; e < 16; ++e) wc[e] = wn_[e];
  }
#pragma unroll
  for (int x = 0; x < 16; ++x)
    SL[((long)bhc * 64 + so + x) * 64 + j] = s[x];
  if (qu == 0) AC[(long)bhc * 64 + j] = Aj;
}

// ---------------- S2a: propagate chunk-boundary states; overwrite SL[c] with S_in(c) ----------------
__global__ __launch_bounds__(256) void scan_prop(
    float* __restrict__ SL, const float* __restrict__ AC,
    const float* __restrict__ initS, float* __restrict__ st1) {
  const int bh = blockIdx.x >> 2;          // 64 bh
  const int jq = blockIdx.x & 3;
  const int h = bh & (NH - 1);
  const int i = threadIdx.x >> 2;
  const int jo = jq * 16 + (threadIdx.x & 3) * 4;
  f32x4 sin4 = *(const f32x4*)(initS + ((long)h * 64 + i) * 64 + jo);
  for (int cc = 0; cc < NCH; ++cc) {
    const long bhc = (long)bh * NCH + cc;
    f32x4* slp = (f32x4*)(SL + (bhc * 64 + i) * 64 + jo);
    const float Ai = AC[bhc * 64 + i];
    f32x4 sl = *slp;
    *slp = sin4;                           // S_in(c) for S2b
    sin4 = Ai * sin4 + sl;
  }
  *(f32x4*)(st1 + ((long)bh * 64 + i) * 64 + jo) = sin4;
}

// ---------------- S2b: cross-chunk correction y += rtil @ S_in ----------------
__global__ __launch_bounds__(256) void scan_corr(
    const float* __restrict__ SL, const u16* __restrict__ rtil, float* __restrict__ ys) {
  __shared__ __align__(16) float S[64 * 64];
  const int bhc = blockIdx.x;
  const int c = bhc & (NCH - 1), h = (bhc >> 4) & (NH - 1), b = bhc >> 8;
  const int tid = threadIdx.x;
  const f32x4* sp = (const f32x4*)(SL + (long)bhc * 4096);
  for (int q = tid; q < 1024; q += 256) ((f32x4*)S)[q] = sp[q];
  __syncthreads();
  const int t = tid >> 2, jg = (tid & 3) * 16;
  const long base = ((long)(b * TTOK + c * CLEN + t) * DD) + h * HD;
  f32x4 yacc[4] = {};
  const u16* rp = rtil + base;
#pragma unroll 8
  for (int i = 0; i < 64; ++i) {
    const float r = b2f(rp[i]);
    const f32x4* srow = (const f32x4*)&S[i * 64 + jg];
#pragma unroll
    for (int e = 0; e < 4; ++e) yacc[e] += r * srow[e];
  }
  f32x4* yp = (f32x4*)(ys + base + jg);
#pragma unroll
  for (int e = 0; e < 4; ++e) yp[e] += yacc[e];
}

// ---------------- GroupNorm(hd=64) * SiLU(g) -> o (bf16) ----------------
__global__ __launch_bounds__(256) void ln_silu(
    const float* __restrict__ ys0, const float* __restrict__ ys1,
    const float* __restrict__ ys2, const float* __restrict__ ys3,
    const u16* __restrict__ gP,
    const float* __restrict__ lnw, const float* __restrict__ lnb,
    u16* __restrict__ oB) {
  const int ridx = blockIdx.x * 4 + (threadIdx.x >> 6);   // (token*16 + h)
  const int lane = threadIdx.x & 63;
  const long basem = (long)ridx * 64;
  const float y = ys0[basem + lane] + ys1[basem + lane] + ys2[basem + lane] + ys3[basem + lane];
  float su = y, sq = y * y;
#pragma unroll
  for (int msk = 1; msk < 64; msk <<= 1) {
    su += __shfl_xor(su, msk, 64);
    sq += __shfl_xor(sq, msk, 64);
  }
  const float mean = su * (1.f / 64.f);
  const float var = sq * (1.f / 64.f) - mean * mean;
  const float rs = rsqrtf(var + 1e-5f);
  const float g = b2f(gP[basem + lane]);
  const float silu = g / (1.f + expf(-g));
  const float val = silu * ((y - mean) * rs * lnw[lane] + lnb[lane]);
  oB[basem + lane] = f2b(val);
}

// ---------------- launcher ----------------
extern "C" void kernel_launch(void* const* d_in, const int* in_sizes, int n_in,
                              void* d_out, int out_size, void* d_ws, size_t ws_size,
                              hipStream_t stream) {
  const float* x   = (const float*)d_in[0];
  const float* xw  = (const float*)d_in[1];
  const float* rW  = (const float*)d_in[2];
  const float* kW  = (const float*)d_in[3];
  const float* vW  = (const float*)d_in[4];
  const float* gW  = (const float*)d_in[5];
  const float* r_la = (const float*)d_in[6],  *r_lb = (const float*)d_in[7],  *r_ll = (const float*)d_in[8];
  const float* k_la = (const float*)d_in[9],  *k_lb = (const float*)d_in[10], *k_ll = (const float*)d_in[11];
  const float* v_la = (const float*)d_in[12], *v_lb = (const float*)d_in[13], *v_ll = (const float*)d_in[14];
  const float* g_la = (const float*)d_in[15], *g_lb = (const float*)d_in[16], *g_ll = (const float*)d_in[17];
  const float* d_la = (const float*)d_in[18], *d_lb = (const float*)d_in[19], *d_ll = (const float*)d_in[20];
  const float* lnw = (const float*)d_in[21];
  const float* lnb = (const float*)d_in[22];
  const float* oW  = (const float*)d_in[23];
  const float* initS = (const float*)d_in[24];
  const float* uP  = (const float*)d_in[25];
  float* out = (float*)d_out;

  // workspace layout (~183 MB; ys1/ys2/ys3 overlay regions dead by scan time)
  char* ws = (char*)d_ws;
  u16*   W_all  = (u16*)(ws + 0);                  // [5][1024][1024] bf16 (r,k,v,g,o)
  u16*   la_all = (u16*)(ws + 10485760);           // [5][64][1024]
  u16*   lb_all = (u16*)(ws + 11141120);           // [5][1024][64]
  float* ll_all = (float*)(ws + 11796480);         // [5][1024]
  u16*   lerpx  = (u16*)(ws + 11816960);           // [4096][1024] bf16 (dead after lora1)
  u16*   xB     = (u16*)(ws + 20205568);           // [4096][1024] bf16 (dead after z-stage2)
  u16*   dxB    = (u16*)(ws + 28594176);           // [4096][1024] bf16 (dead after z-stage2)
  u16*   t1_all = (u16*)(ws + 36982784);           // [5][4096][64] bf16
  u16*   z_all  = (u16*)(ws + 39604224);           // [5][4096][1024] bf16 (dead after projections)
  u16*   rkvg   = (u16*)(ws + 81547264);           // [4][4096][1024] bf16
  float* wbuf   = (float*)(ws + 115101696);        // [4096][1024] f32
  u16*   rtil   = (u16*)(ws + 131878912);          // [4096][1024] bf16
  float* SL     = (float*)(ws + 140267520);        // [1024][64][64] f32
  float* AC     = (float*)(ws + 157044736);        // [1024][64] f32
  float* ys0    = (float*)(ws + 157306880);        // [4096][1024] f32
  u16*   oB     = (u16*)(ws + 174084096);          // [4096][1024] bf16
  float* ys1    = (float*)(ws + 11816960);         // overlay: lerpx+xB
  float* ys2    = (float*)(ws + 39604224);         // overlay: z_all[0..]
  float* ys3    = (float*)(ws + 56381440);         // overlay: z_all[..]

  convW<<<5120, 256, 0, stream>>>(rW, kW, vW, gW, oW, W_all);
  convLora<<<645, 256, 0, stream>>>(r_la, k_la, v_la, g_la, d_la,
                                    r_lb, k_lb, v_lb, g_lb, d_lb,
                                    r_ll, k_ll, v_ll, g_ll, d_ll,
                                    la_all, lb_all, ll_all);
  prep<<<4096, 256, 0, stream>>>(x, xw, lerpx, xB, dxB);

  // LoRA stage 1 (all 5): t1 = tanh(lerpx @ la^T)      [4096 x 64]
  gemm2<64, 64, 1><<<dim3(1, 64, 5), 256, 0, stream>>>(
      lerpx, 0L, la_all, 65536L, (void*)t1_all, 262144L, nullptr, nullptr, nullptr, MT, 64, 1024);
  // LoRA stage 2 (all 5): z = bf16(x + dx*(ll + t1 @ lb^T))   [4096 x 1024]
  gemm2<128, 128, 2><<<dim3(8, 32, 5), 256, 0, stream>>>(
      t1_all, 262144L, lb_all, 65536L, (void*)z_all, 4194304L, ll_all, xB, dxB, MT, 1024, 64);
  // d-outer stage 1: t2 = tanh(z_d @ d_la^T)
  gemm2<64, 64, 1><<<dim3(1, 64, 1), 256, 0, stream>>>(
      z_all + 4L * 4194304, 0L, la_all + 4L * 65536, 0L, (void*)t1_all, 0L, nullptr, nullptr, nullptr, MT, 64, 1024);
  // d-outer stage 2: w = exp(-exp(d_ll + t2 @ d_lb^T))  (f32)
  gemm2<128, 128, 3><<<dim3(8, 32, 1), 256, 0, stream>>>(
      t1_all, 0L, lb_all + 4L * 65536, 0L, (void*)wbuf, 0L, ll_all + 4096, nullptr, nullptr, MT, 1024, 64);
  // projections r,k,v,g = z @ W^T (bf16 out)
  gemm2<128, 128, 4><<<dim3(8, 32, 4), 256, 0, stream>>>(
      z_all, 4194304L, W_all, 1048576L, (void*)rkvg, 4194304L, nullptr, nullptr, nullptr, MT, 1024, 1024);

  // chunked WKV scan
  scan_local<<<1024, 256, 0, stream>>>(rkvg, rkvg + 4194304L, rkvg + 2L * 4194304, wbuf,
                                       uP, ys0, ys1, ys2, ys3, rtil, SL, AC);
  scan_prop<<<256, 256, 0, stream>>>(SL, AC, initS, out + 4194304);
  scan_corr<<<1024, 256, 0, stream>>>(SL, rtil, ys0);

  // o = silu(g) * groupnorm(y); out = o @ oW^T
  ln_silu<<<16384, 256, 0, stream>>>(ys0, ys1, ys2, ys3, rkvg + 3L * 4194304, lnw, lnb, oB);
  gemm2<128, 128, 0><<<dim3(8, 32, 1), 256, 0, stream>>>(
      oB, 0L, W_all + 4L * 1048576, 0L, (void*)out, 0L, nullptr, nullptr, nullptr, MT, 1024, 1024);
}

// Round 5
// 368.441 us; speedup vs baseline: 1.3258x; 1.0542x over previous
//
#include <hip/hip_runtime.h>
#include <hip/hip_bf16.h>

typedef unsigned short u16;
typedef unsigned int u32;
typedef __attribute__((ext_vector_type(4))) float f32x4;
typedef __attribute__((ext_vector_type(4))) u32 u32x4;
typedef __attribute__((ext_vector_type(8))) short s16x8;

#define AS1 __attribute__((address_space(1)))
#define AS3 __attribute__((address_space(3)))

#define NB 4
#define TTOK 1024
#define DD 1024
#define NH 16
#define HD 64
#define MT 4096      // B*T tokens
#define NCH 16       // chunks per (b,h)
#define CLEN 64      // chunk length

static __device__ __forceinline__ float b2f(u16 u) {
  union { unsigned int u; float f; } c; c.u = ((unsigned int)u) << 16; return c.f;
}
static __device__ __forceinline__ float ubit(u32 u) {
  union { u32 u; float f; } c; c.u = u; return c.f;
}
static __device__ __forceinline__ u16 f2b(float f) {
  union { float f; unsigned int u; } c; c.f = f;
  return (u16)((c.u + 0x7fffu + ((c.u >> 16) & 1u)) >> 16);
}
// direct global->LDS async copy, 16B per lane
static __device__ __forceinline__ void gload16(const u16* g, u16* l) {
  __builtin_amdgcn_global_load_lds((const AS1 u32*)g, (AS3 u32*)l, 16, 0, 0);
}
// LDS byte-offset swizzle (involution, keeps 16B chunks intact)
static __device__ __forceinline__ int swz(int lin) {
  return lin ^ (((lin >> 9) & 3) << 5) ^ (((lin >> 7) & 1) << 4);
}

// ---------------- weight conversion / packing ----------------
__global__ __launch_bounds__(256) void convW(const float* __restrict__ s0, const float* __restrict__ s1,
                                             const float* __restrict__ s2, const float* __restrict__ s3,
                                             const float* __restrict__ s4, u16* __restrict__ dst) {
  long f = ((long)blockIdx.x * 256 + threadIdx.x) << 2;   // 5 * 1048576 elems
  int sel = (int)(f >> 20);
  const float* s = sel == 0 ? s0 : sel == 1 ? s1 : sel == 2 ? s2 : sel == 3 ? s3 : s4;
  long off = f & 1048575;
  f32x4 v = *(const f32x4*)&s[off];
  ushort4 o; o.x = f2b(v[0]); o.y = f2b(v[1]); o.z = f2b(v[2]); o.w = f2b(v[3]);
  *(ushort4*)&dst[f] = o;
}

__global__ __launch_bounds__(256) void convLora(
    const float* a0, const float* a1, const float* a2, const float* a3, const float* a4,
    const float* b0, const float* b1, const float* b2, const float* b3, const float* b4,
    const float* l0, const float* l1, const float* l2, const float* l3, const float* l4,
    u16* __restrict__ laD, u16* __restrict__ lbD, float* __restrict__ llD) {
  long f = ((long)blockIdx.x * 256 + threadIdx.x) << 2;
  if (f < 327680) {            // 5 x 65536 la
    int sel = (int)(f >> 16); long off = f & 65535;
    const float* s = sel == 0 ? a0 : sel == 1 ? a1 : sel == 2 ? a2 : sel == 3 ? a3 : a4;
    f32x4 v = *(const f32x4*)&s[off];
    ushort4 o; o.x = f2b(v[0]); o.y = f2b(v[1]); o.z = f2b(v[2]); o.w = f2b(v[3]);
    *(ushort4*)&laD[f] = o;
  } else if (f < 655360) {     // 5 x 65536 lb
    long g = f - 327680;
    int sel = (int)(g >> 16); long off = g & 65535;
    const float* s = sel == 0 ? b0 : sel == 1 ? b1 : sel == 2 ? b2 : sel == 3 ? b3 : b4;
    f32x4 v = *(const f32x4*)&s[off];
    ushort4 o; o.x = f2b(v[0]); o.y = f2b(v[1]); o.z = f2b(v[2]); o.w = f2b(v[3]);
    *(ushort4*)&lbD[g] = o;
  } else if (f < 660480) {     // 5 x 1024 ll (f32 copy)
    long g = f - 655360;
    int sel = (int)(g >> 10); long off = g & 1023;
    const float* s = sel == 0 ? l0 : sel == 1 ? l1 : sel == 2 ? l2 : sel == 3 ? l3 : l4;
    *(f32x4*)&llD[g] = *(const f32x4*)&s[off];
  }
}

// ---------------- token shift prep: lerpx, xB, dxB (all bf16) ----------------
__global__ __launch_bounds__(256) void prep(const float* __restrict__ x, const float* __restrict__ xw,
                                            u16* __restrict__ lerpx, u16* __restrict__ xB,
                                            u16* __restrict__ dxB) {
  long f = ((long)blockIdx.x * 256 + threadIdx.x) << 2;
  int d = (int)(f & (DD - 1));
  int m = (int)(f >> 10);
  int t = m & (TTOK - 1);
  f32x4 xv = *(const f32x4*)&x[f];
  f32x4 xm = {};
  if (t > 0) xm = *(const f32x4*)&x[f - DD];
  f32x4 xwv = *(const f32x4*)&xw[d];
  f32x4 dx = xm - xv;
  f32x4 lp = xv + dx * xwv;
  ushort4 o; o.x = f2b(lp[0]); o.y = f2b(lp[1]); o.z = f2b(lp[2]); o.w = f2b(lp[3]);
  *(ushort4*)&lerpx[f] = o;
  ushort4 ox; ox.x = f2b(xv[0]); ox.y = f2b(xv[1]); ox.z = f2b(xv[2]); ox.w = f2b(xv[3]);
  *(ushort4*)&xB[f] = ox;
  ushort4 od; od.x = f2b(dx[0]); od.y = f2b(dx[1]); od.z = f2b(dx[2]); od.w = f2b(dx[3]);
  *(ushort4*)&dxB[f] = od;
}

// ---------------- bf16 MFMA GEMM, m97-style: BK=64, global_load_lds, swizzled LDS ----
// C[m][n] = sum_k A[m][k]*B[n][k].
// EPI: 0 = store f32; 1 = store bf16(tanh); 2 = z-epilogue bf16(x + dx*(ll+acc));
//      3 = store f32 exp(-exp(ll+acc)); 4 = store bf16
template<int BM, int BN, int EPI>
__launch_bounds__(256)
__global__ void gemm2(const u16* __restrict__ Ab, long sAz,
                      const u16* __restrict__ Bb, long sBz,
                      void* __restrict__ Ob, long sOz,
                      const float* __restrict__ llb,
                      const u16* __restrict__ xB,
                      const u16* __restrict__ dxB,
                      int M, int N, int K) {
  __shared__ __align__(16) u16 As[BM * 64];
  __shared__ __align__(16) u16 Bs[BN * 64];
  const int z = blockIdx.z;
  const u16* A = Ab + (long)z * sAz;
  const u16* Bw = Bb + (long)z * sBz;
  const int m0 = blockIdx.y * BM;
  const int n0 = blockIdx.x * BN;
  const int tid = threadIdx.x;
  const int l = tid & 63;
  const int wv = tid >> 6;
  constexpr int WM = BM / 2, WN = BN / 2;
  constexpr int FM = WM / 16, FN = WN / 16;
  const int wm0 = (wv >> 1) * WM, wn0 = (wv & 1) * WN;
  const int lrow = l & 15, lk = (l >> 4) * 8;
  constexpr int GA = BM / 32, GB = BN / 32;   // 16B gloads per thread per tile
  int gA[GA], gB[GB];
#pragma unroll
  for (int q = 0; q < GA; ++q) {
    int d = (q * 256 + tid) * 16;
    int bb = swz(d);
    gA[q] = (m0 + (bb >> 7)) * K + ((bb & 127) >> 1);
  }
#pragma unroll
  for (int q = 0; q < GB; ++q) {
    int d = (q * 256 + tid) * 16;
    int bb = swz(d);
    gB[q] = (n0 + (bb >> 7)) * K + ((bb & 127) >> 1);
  }
  int aOff[FM][2], bOff[FN][2];
#pragma unroll
  for (int m = 0; m < FM; ++m)
#pragma unroll
    for (int kk = 0; kk < 2; ++kk)
      aOff[m][kk] = swz(((wm0 + m * 16 + lrow) << 7) + (kk << 6) + (lk << 1));
#pragma unroll
  for (int n = 0; n < FN; ++n)
#pragma unroll
    for (int kk = 0; kk < 2; ++kk)
      bOff[n][kk] = swz(((wn0 + n * 16 + lrow) << 7) + (kk << 6) + (lk << 1));
  f32x4 acc[FM][FN] = {};
  for (int k0 = 0; k0 < K; k0 += 64) {
    __syncthreads();
#pragma unroll
    for (int q = 0; q < GA; ++q)
      gload16(&A[(long)gA[q] + k0], (u16*)((char*)As + (q * 256 + tid) * 16));
#pragma unroll
    for (int q = 0; q < GB; ++q)
      gload16(&Bw[(long)gB[q] + k0], (u16*)((char*)Bs + (q * 256 + tid) * 16));
    __syncthreads();   // drains vmcnt -> LDS tile complete
#pragma unroll
    for (int kk = 0; kk < 2; ++kk) {
      s16x8 af[FM], bfr[FN];
#pragma unroll
      for (int m = 0; m < FM; ++m) af[m] = *(const s16x8*)((const char*)As + aOff[m][kk]);
#pragma unroll
      for (int n = 0; n < FN; ++n) bfr[n] = *(const s16x8*)((const char*)Bs + bOff[n][kk]);
#pragma unroll
      for (int m = 0; m < FM; ++m)
#pragma unroll
        for (int n = 0; n < FN; ++n)
          acc[m][n] = __builtin_amdgcn_mfma_f32_16x16x32_bf16(af[m], bfr[n], acc[m][n], 0, 0, 0);
    }
  }
#pragma unroll
  for (int m = 0; m < FM; ++m) {
#pragma unroll
    for (int n = 0; n < FN; ++n) {
      const int j = n0 + wn0 + n * 16 + lrow;
#pragma unroll
      for (int q = 0; q < 4; ++q) {
        const int i = m0 + wm0 + m * 16 + (l >> 4) * 4 + q;
        const long off = (long)i * N + j;
        float v = acc[m][n][q];
        if constexpr (EPI == 0) {
          ((float*)Ob + (long)z * sOz)[off] = v;
        } else if constexpr (EPI == 1) {
          ((u16*)Ob + (long)z * sOz)[off] = f2b(tanhf(v));
        } else if constexpr (EPI == 2) {
          float val = b2f(xB[off]) + b2f(dxB[off]) * (llb[(long)z * N + j] + v);
          ((u16*)Ob + (long)z * sOz)[off] = f2b(val);
        } else if constexpr (EPI == 3) {
          ((float*)Ob + (long)z * sOz)[off] = expf(-expf(llb[j] + v));
        } else {
          ((u16*)Ob + (long)z * sOz)[off] = f2b(v);
        }
      }
    }
  }
}

// ---------------- S1: chunk-local WKV scan, LDS-staged, 4 waves/block i-split ------
// Whole chunk (r,k,v bf16 + w f32 = 40KB) bulk-staged to LDS via global_load_lds;
// 64-step loop runs from LDS: wave-uniform ds_read broadcasts for the wave's 16
// state rows, per-lane reads for v. Partial y written bf16 (summed in ln_silu).
__global__ __launch_bounds__(256) void scan_local(
    const u16* __restrict__ rP, const u16* __restrict__ kP,
    const u16* __restrict__ vP, const float* __restrict__ wP,
    const float* __restrict__ uP,
    u16* __restrict__ ys0, u16* __restrict__ ys1,
    u16* __restrict__ ys2, u16* __restrict__ ys3,
    u16* __restrict__ rtil, float* __restrict__ SL, float* __restrict__ AC) {
  __shared__ __align__(16) u16 Rs[64 * 64];
  __shared__ __align__(16) u16 Ks[64 * 64];
  __shared__ __align__(16) u16 Vs[64 * 64];
  __shared__ __align__(16) float Ws[64 * 64];
  const int bhc = blockIdx.x;
  const int c = bhc & (NCH - 1), h = (bhc >> 4) & (NH - 1), b = bhc >> 8;
  const int tid = threadIdx.x;
  const int j = tid & 63;
  const int qu = tid >> 6;
  const long base0 = ((long)(b * TTOK + c * CLEN) << 10) + h * HD;
  // ---- bulk stage chunk into LDS ----
#pragma unroll
  for (int q = 0; q < 2; ++q) {            // r,k,v: 512 x 16B chunks each
    int cidx = q * 256 + tid;
    int t = cidx >> 3, off = (cidx & 7) * 8;
    gload16(&rP[base0 + (long)t * DD + off], (u16*)Rs + cidx * 8);
    gload16(&kP[base0 + (long)t * DD + off], (u16*)Ks + cidx * 8);
    gload16(&vP[base0 + (long)t * DD + off], (u16*)Vs + cidx * 8);
  }
#pragma unroll
  for (int q = 0; q < 4; ++q) {            // w: 1024 x 16B chunks
    int cidx = q * 256 + tid;
    int t = cidx >> 4, off = (cidx & 15) * 4;
    __builtin_amdgcn_global_load_lds((const AS1 u32*)&wP[base0 + (long)t * DD + off],
                                     (AS3 u32*)((float*)Ws + cidx * 4), 16, 0, 0);
  }
  __syncthreads();                          // vmcnt(0) drain -> LDS ready
  const int so = qu * 16;
  float s[16];
#pragma unroll
  for (int x = 0; x < 16; ++x) s[x] = 0.f;
  float Aj = 1.f;
  const float uj = uP[h * HD + j];
  long base = base0;
  u16* __restrict__ ysel = qu == 0 ? ys0 : qu == 1 ? ys1 : qu == 2 ? ys2 : ys3;
  for (int tt = 0; tt < CLEN; ++tt) {
    const int ro = tt * 64 + so;
    u32x4 ra = *(const u32x4*)&Rs[ro];       // wave-uniform addr -> broadcast
    u32x4 rb = *(const u32x4*)&Rs[ro + 8];
    u32x4 ka = *(const u32x4*)&Ks[ro];
    u32x4 kb = *(const u32x4*)&Ks[ro + 8];
    float wl[16];
#pragma unroll
    for (int e = 0; e < 4; ++e) *(f32x4*)&wl[e * 4] = *(const f32x4*)&Ws[ro + e * 4];
    const float vj = b2f(Vs[tt * 64 + j]);
    float ya = 0.f, yb = 0.f;
#pragma unroll
    for (int e = 0; e < 4; ++e) {
      const float r0 = ubit(ra[e] << 16), r1 = ubit(ra[e] & 0xffff0000u);
      const float k0 = ubit(ka[e] << 16), k1 = ubit(ka[e] & 0xffff0000u);
      ya = fmaf(r0, s[2 * e], ya);
      s[2 * e] = fmaf(wl[2 * e], s[2 * e], k0 * vj);
      yb = fmaf(r1, s[2 * e + 1], yb);
      s[2 * e + 1] = fmaf(wl[2 * e + 1], s[2 * e + 1], k1 * vj);
    }
#pragma unroll
    for (int e = 0; e < 4; ++e) {
      const float r0 = ubit(rb[e] << 16), r1 = ubit(rb[e] & 0xffff0000u);
      const float k0 = ubit(kb[e] << 16), k1 = ubit(kb[e] & 0xffff0000u);
      ya = fmaf(r0, s[8 + 2 * e], ya);
      s[8 + 2 * e] = fmaf(wl[8 + 2 * e], s[8 + 2 * e], k0 * vj);
      yb = fmaf(r1, s[8 + 2 * e + 1], yb);
      s[8 + 2 * e + 1] = fmaf(wl[8 + 2 * e + 1], s[8 + 2 * e + 1], k1 * vj);
    }
    float y = ya + yb;
    if (qu == 0) {
      const float rj = b2f(Rs[tt * 64 + j]);
      const float kj = b2f(Ks[tt * 64 + j]);
      const float wj = Ws[tt * 64 + j];
      rtil[base + j] = f2b(rj * Aj);         // r_t * A_{t-1}
      float al = rj * uj * kj;               // u-term: (sum_i r_i u_i k_i) * v_j
#pragma unroll
      for (int msk = 1; msk < 64; msk <<= 1) al += __shfl_xor(al, msk, 64);
      y = fmaf(al, vj, y);
      Aj *= wj;
    }
    ysel[base + j] = f2b(y);
    base += DD;
  }
#pragma unroll
  for (int x = 0; x < 16; ++x)
    SL[((long)bhc * 64 + so + x) * 64 + j] = s[x];
  if (qu == 0) AC[(long)bhc * 64 + j] = Aj;
}

// ---------------- S2a: propagate chunk-boundary states; overwrite SL[c] with S_in(c) ----------------
__global__ __launch_bounds__(256) void scan_prop(
    float* __restrict__ SL, const float* __restrict__ AC,
    const float* __restrict__ initS, float* __restrict__ st1) {
  const int bh = blockIdx.x >> 2;          // 64 bh
  const int jq = blockIdx.x & 3;
  const int h = bh & (NH - 1);
  const int i = threadIdx.x >> 2;
  const int jo = jq * 16 + (threadIdx.x & 3) * 4;
  f32x4 sin4 = *(const f32x4*)(initS + ((long)h * 64 + i) * 64 + jo);
  for (int cc = 0; cc < NCH; ++cc) {
    const long bhc = (long)bh * NCH + cc;
    f32x4* slp = (f32x4*)(SL + (bhc * 64 + i) * 64 + jo);
    const float Ai = AC[bhc * 64 + i];
    f32x4 sl = *slp;
    *slp = sin4;                           // S_in(c) for S2b
    sin4 = Ai * sin4 + sl;
  }
  *(f32x4*)(st1 + ((long)bh * 64 + i) * 64 + jo) = sin4;
}

// ---------------- S2b: cross-chunk correction ysC = rtil @ S_in (store, f32) -------
__global__ __launch_bounds__(256) void scan_corr(
    const float* __restrict__ SL, const u16* __restrict__ rtil, float* __restrict__ ysC) {
  __shared__ __align__(16) float S[64 * 64];
  const int bhc = blockIdx.x;
  const int c = bhc & (NCH - 1), h = (bhc >> 4) & (NH - 1), b = bhc >> 8;
  const int tid = threadIdx.x;
  const f32x4* sp = (const f32x4*)(SL + (long)bhc * 4096);
  for (int q = tid; q < 1024; q += 256) ((f32x4*)S)[q] = sp[q];
  __syncthreads();
  const int t = tid >> 2, jg = (tid & 3) * 16;
  const long base = ((long)(b * TTOK + c * CLEN + t) * DD) + h * HD;
  f32x4 yacc[4] = {};
  const u16* rp = rtil + base;
#pragma unroll 8
  for (int i = 0; i < 64; ++i) {
    const float r = b2f(rp[i]);
    const f32x4* srow = (const f32x4*)&S[i * 64 + jg];
#pragma unroll
    for (int e = 0; e < 4; ++e) yacc[e] += r * srow[e];
  }
  f32x4* yp = (f32x4*)(ysC + base + jg);
#pragma unroll
  for (int e = 0; e < 4; ++e) yp[e] = yacc[e];
}

// ---------------- GroupNorm(hd=64) * SiLU(g) -> o (bf16) ----------------
__global__ __launch_bounds__(256) void ln_silu(
    const u16* __restrict__ p0, const u16* __restrict__ p1,
    const u16* __restrict__ p2, const u16* __restrict__ p3,
    const float* __restrict__ ysC,
    const u16* __restrict__ gP,
    const float* __restrict__ lnw, const float* __restrict__ lnb,
    u16* __restrict__ oB) {
  const int ridx = blockIdx.x * 4 + (threadIdx.x >> 6);   // (token*16 + h)
  const int lane = threadIdx.x & 63;
  const long basem = (long)ridx * 64;
  const float y = b2f(p0[basem + lane]) + b2f(p1[basem + lane]) +
                  b2f(p2[basem + lane]) + b2f(p3[basem + lane]) + ysC[basem + lane];
  float su = y, sq = y * y;
#pragma unroll
  for (int msk = 1; msk < 64; msk <<= 1) {
    su += __shfl_xor(su, msk, 64);
    sq += __shfl_xor(sq, msk, 64);
  }
  const float mean = su * (1.f / 64.f);
  const float var = sq * (1.f / 64.f) - mean * mean;
  const float rs = rsqrtf(var + 1e-5f);
  const float g = b2f(gP[basem + lane]);
  const float silu = g / (1.f + expf(-g));
  const float val = silu * ((y - mean) * rs * lnw[lane] + lnb[lane]);
  oB[basem + lane] = f2b(val);
}

// ---------------- launcher ----------------
extern "C" void kernel_launch(void* const* d_in, const int* in_sizes, int n_in,
                              void* d_out, int out_size, void* d_ws, size_t ws_size,
                              hipStream_t stream) {
  const float* x   = (const float*)d_in[0];
  const float* xw  = (const float*)d_in[1];
  const float* rW  = (const float*)d_in[2];
  const float* kW  = (const float*)d_in[3];
  const float* vW  = (const float*)d_in[4];
  const float* gW  = (const float*)d_in[5];
  const float* r_la = (const float*)d_in[6],  *r_lb = (const float*)d_in[7],  *r_ll = (const float*)d_in[8];
  const float* k_la = (const float*)d_in[9],  *k_lb = (const float*)d_in[10], *k_ll = (const float*)d_in[11];
  const float* v_la = (const float*)d_in[12], *v_lb = (const float*)d_in[13], *v_ll = (const float*)d_in[14];
  const float* g_la = (const float*)d_in[15], *g_lb = (const float*)d_in[16], *g_ll = (const float*)d_in[17];
  const float* d_la = (const float*)d_in[18], *d_lb = (const float*)d_in[19], *d_ll = (const float*)d_in[20];
  const float* lnw = (const float*)d_in[21];
  const float* lnb = (const float*)d_in[22];
  const float* oW  = (const float*)d_in[23];
  const float* initS = (const float*)d_in[24];
  const float* uP  = (const float*)d_in[25];
  float* out = (float*)d_out;

  // workspace layout (~183 MB; bf16 partial-ys overlay dead regions)
  char* ws = (char*)d_ws;
  u16*   W_all  = (u16*)(ws + 0);                  // [5][1024][1024] bf16 (r,k,v,g,o)
  u16*   la_all = (u16*)(ws + 10485760);           // [5][64][1024]
  u16*   lb_all = (u16*)(ws + 11141120);           // [5][1024][64]
  float* ll_all = (float*)(ws + 11796480);         // [5][1024]
  u16*   lerpx  = (u16*)(ws + 11816960);           // [4096][1024] bf16 (dead after lora1)
  u16*   xB     = (u16*)(ws + 20205568);           // [4096][1024] bf16 (dead after z-stage2)
  u16*   dxB    = (u16*)(ws + 28594176);           // [4096][1024] bf16 (dead after z-stage2)
  u16*   t1_all = (u16*)(ws + 36982784);           // [5][4096][64] bf16
  u16*   z_all  = (u16*)(ws + 39604224);           // [5][4096][1024] bf16 (dead after projections)
  u16*   rkvg   = (u16*)(ws + 81547264);           // [4][4096][1024] bf16
  float* wbuf   = (float*)(ws + 115101696);        // [4096][1024] f32 (dead after scan_local)
  u16*   rtil   = (u16*)(ws + 131878912);          // [4096][1024] bf16
  float* SL     = (float*)(ws + 140267520);        // [1024][64][64] f32
  float* AC     = (float*)(ws + 157044736);        // [1024][64] f32
  u16*   ys0p   = (u16*)(ws + 157306880);          // [4096][1024] bf16 partial
  u16*   oB     = (u16*)(ws + 174084096);          // [4096][1024] bf16
  u16*   ys1p   = (u16*)(ws + 11816960);           // overlay: lerpx
  u16*   ys2p   = (u16*)(ws + 39604224);           // overlay: z_all[0]
  u16*   ys3p   = (u16*)(ws + 47992832);           // overlay: z_all[1]
  float* ysC    = (float*)(ws + 115101696);        // overlay: wbuf (f32 correction)

  convW<<<5120, 256, 0, stream>>>(rW, kW, vW, gW, oW, W_all);
  convLora<<<645, 256, 0, stream>>>(r_la, k_la, v_la, g_la, d_la,
                                    r_lb, k_lb, v_lb, g_lb, d_lb,
                                    r_ll, k_ll, v_ll, g_ll, d_ll,
                                    la_all, lb_all, ll_all);
  prep<<<4096, 256, 0, stream>>>(x, xw, lerpx, xB, dxB);

  // LoRA stage 1 (all 5): t1 = tanh(lerpx @ la^T)      [4096 x 64]
  gemm2<64, 64, 1><<<dim3(1, 64, 5), 256, 0, stream>>>(
      lerpx, 0L, la_all, 65536L, (void*)t1_all, 262144L, nullptr, nullptr, nullptr, MT, 64, 1024);
  // LoRA stage 2 (all 5): z = bf16(x + dx*(ll + t1 @ lb^T))   [4096 x 1024]
  gemm2<128, 128, 2><<<dim3(8, 32, 5), 256, 0, stream>>>(
      t1_all, 262144L, lb_all, 65536L, (void*)z_all, 4194304L, ll_all, xB, dxB, MT, 1024, 64);
  // d-outer stage 1: t2 = tanh(z_d @ d_la^T)
  gemm2<64, 64, 1><<<dim3(1, 64, 1), 256, 0, stream>>>(
      z_all + 4L * 4194304, 0L, la_all + 4L * 65536, 0L, (void*)t1_all, 0L, nullptr, nullptr, nullptr, MT, 64, 1024);
  // d-outer stage 2: w = exp(-exp(d_ll + t2 @ d_lb^T))  (f32)
  gemm2<128, 128, 3><<<dim3(8, 32, 1), 256, 0, stream>>>(
      t1_all, 0L, lb_all + 4L * 65536, 0L, (void*)wbuf, 0L, ll_all + 4096, nullptr, nullptr, MT, 1024, 64);
  // projections r,k,v,g = z @ W^T (bf16 out)
  gemm2<128, 128, 4><<<dim3(8, 32, 4), 256, 0, stream>>>(
      z_all, 4194304L, W_all, 1048576L, (void*)rkvg, 4194304L, nullptr, nullptr, nullptr, MT, 1024, 1024);

  // chunked WKV scan
  scan_local<<<1024, 256, 0, stream>>>(rkvg, rkvg + 4194304L, rkvg + 2L * 4194304, wbuf,
                                       uP, ys0p, ys1p, ys2p, ys3p, rtil, SL, AC);
  scan_prop<<<256, 256, 0, stream>>>(SL, AC, initS, out + 4194304);
  scan_corr<<<1024, 256, 0, stream>>>(SL, rtil, ysC);

  // o = silu(g) * groupnorm(y); out = o @ oW^T
  ln_silu<<<16384, 256, 0, stream>>>(ys0p, ys1p, ys2p, ys3p, ysC, rkvg + 3L * 4194304, lnw, lnb, oB);
  gemm2<128, 128, 0><<<dim3(8, 32, 1), 256, 0, stream>>>(
      oB, 0L, W_all + 4L * 1048576, 0L, (void*)out, 0L, nullptr, nullptr, nullptr, MT, 1024, 1024);
}

// Round 6
// 352.404 us; speedup vs baseline: 1.3862x; 1.0455x over previous
//
#include <hip/hip_runtime.h>
#include <hip/hip_bf16.h>

typedef unsigned short u16;
typedef unsigned int u32;
typedef __attribute__((ext_vector_type(2))) float f32x2;
typedef __attribute__((ext_vector_type(4))) float f32x4;
typedef __attribute__((ext_vector_type(4))) u32 u32x4;
typedef __attribute__((ext_vector_type(8))) short s16x8;

#define AS1 __attribute__((address_space(1)))
#define AS3 __attribute__((address_space(3)))

#define NB 4
#define TTOK 1024
#define DD 1024
#define NH 16
#define HD 64
#define MT 4096      // B*T tokens
#define NCH 16       // chunks per (b,h)
#define CLEN 64      // chunk length

struct Ptr8 { u16* p[8]; };
struct CPtr8 { const u16* p[8]; };

static __device__ __forceinline__ float b2f(u16 u) {
  union { unsigned int u; float f; } c; c.u = ((unsigned int)u) << 16; return c.f;
}
static __device__ __forceinline__ float ubit(u32 u) {
  union { u32 u; float f; } c; c.u = u; return c.f;
}
static __device__ __forceinline__ u16 f2b(float f) {
  union { float f; unsigned int u; } c; c.f = f;
  return (u16)((c.u + 0x7fffu + ((c.u >> 16) & 1u)) >> 16);
}
// direct global->LDS async copy, 16B per lane
static __device__ __forceinline__ void gload16(const u16* g, u16* l) {
  __builtin_amdgcn_global_load_lds((const AS1 u32*)g, (AS3 u32*)l, 16, 0, 0);
}
// LDS byte-offset swizzle (involution, keeps 16B chunks intact)
static __device__ __forceinline__ int swz(int lin) {
  return lin ^ (((lin >> 9) & 3) << 5) ^ (((lin >> 7) & 1) << 4);
}

// ---------------- weight conversion / packing ----------------
__global__ __launch_bounds__(256) void convW(const float* __restrict__ s0, const float* __restrict__ s1,
                                             const float* __restrict__ s2, const float* __restrict__ s3,
                                             const float* __restrict__ s4, u16* __restrict__ dst) {
  long f = ((long)blockIdx.x * 256 + threadIdx.x) << 2;   // 5 * 1048576 elems
  int sel = (int)(f >> 20);
  const float* s = sel == 0 ? s0 : sel == 1 ? s1 : sel == 2 ? s2 : sel == 3 ? s3 : s4;
  long off = f & 1048575;
  f32x4 v = *(const f32x4*)&s[off];
  ushort4 o; o.x = f2b(v[0]); o.y = f2b(v[1]); o.z = f2b(v[2]); o.w = f2b(v[3]);
  *(ushort4*)&dst[f] = o;
}

__global__ __launch_bounds__(256) void convLora(
    const float* a0, const float* a1, const float* a2, const float* a3, const float* a4,
    const float* b0, const float* b1, const float* b2, const float* b3, const float* b4,
    const float* l0, const float* l1, const float* l2, const float* l3, const float* l4,
    u16* __restrict__ laD, u16* __restrict__ lbD, float* __restrict__ llD) {
  long f = ((long)blockIdx.x * 256 + threadIdx.x) << 2;
  if (f < 327680) {            // 5 x 65536 la
    int sel = (int)(f >> 16); long off = f & 65535;
    const float* s = sel == 0 ? a0 : sel == 1 ? a1 : sel == 2 ? a2 : sel == 3 ? a3 : a4;
    f32x4 v = *(const f32x4*)&s[off];
    ushort4 o; o.x = f2b(v[0]); o.y = f2b(v[1]); o.z = f2b(v[2]); o.w = f2b(v[3]);
    *(ushort4*)&laD[f] = o;
  } else if (f < 655360) {     // 5 x 65536 lb
    long g = f - 327680;
    int sel = (int)(g >> 16); long off = g & 65535;
    const float* s = sel == 0 ? b0 : sel == 1 ? b1 : sel == 2 ? b2 : sel == 3 ? b3 : b4;
    f32x4 v = *(const f32x4*)&s[off];
    ushort4 o; o.x = f2b(v[0]); o.y = f2b(v[1]); o.z = f2b(v[2]); o.w = f2b(v[3]);
    *(ushort4*)&lbD[g] = o;
  } else if (f < 660480) {     // 5 x 1024 ll (f32 copy)
    long g = f - 655360;
    int sel = (int)(g >> 10); long off = g & 1023;
    const float* s = sel == 0 ? l0 : sel == 1 ? l1 : sel == 2 ? l2 : sel == 3 ? l3 : l4;
    *(f32x4*)&llD[g] = *(const f32x4*)&s[off];
  }
}

// ---------------- token shift prep: lerpx, xB, dxB (all bf16) ----------------
__global__ __launch_bounds__(256) void prep(const float* __restrict__ x, const float* __restrict__ xw,
                                            u16* __restrict__ lerpx, u16* __restrict__ xB,
                                            u16* __restrict__ dxB) {
  long f = ((long)blockIdx.x * 256 + threadIdx.x) << 2;
  int d = (int)(f & (DD - 1));
  int m = (int)(f >> 10);
  int t = m & (TTOK - 1);
  f32x4 xv = *(const f32x4*)&x[f];
  f32x4 xm = {};
  if (t > 0) xm = *(const f32x4*)&x[f - DD];
  f32x4 xwv = *(const f32x4*)&xw[d];
  f32x4 dx = xm - xv;
  f32x4 lp = xv + dx * xwv;
  ushort4 o; o.x = f2b(lp[0]); o.y = f2b(lp[1]); o.z = f2b(lp[2]); o.w = f2b(lp[3]);
  *(ushort4*)&lerpx[f] = o;
  ushort4 ox; ox.x = f2b(xv[0]); ox.y = f2b(xv[1]); ox.z = f2b(xv[2]); ox.w = f2b(xv[3]);
  *(ushort4*)&xB[f] = ox;
  ushort4 od; od.x = f2b(dx[0]); od.y = f2b(dx[1]); od.z = f2b(dx[2]); od.w = f2b(dx[3]);
  *(ushort4*)&dxB[f] = od;
}

// ---------------- bf16 MFMA GEMM, m97-style: BK=64, global_load_lds, swizzled LDS ----
// C[m][n] = sum_k A[m][k]*B[n][k].   blockIdx.x -> M tile (A-panel sharers co-XCD).
// EPI: 0 = store f32; 1 = store bf16(tanh); 2 = z-epilogue bf16(x + dx*(ll+acc));
//      3 = store f32 exp(-exp(ll+acc)); 4 = store bf16
template<int BM, int BN, int EPI>
__launch_bounds__(256)
__global__ void gemm2(const u16* __restrict__ Ab, long sAz,
                      const u16* __restrict__ Bb, long sBz,
                      void* __restrict__ Ob, long sOz,
                      const float* __restrict__ llb,
                      const u16* __restrict__ xB,
                      const u16* __restrict__ dxB,
                      int M, int N, int K) {
  __shared__ __align__(16) u16 As[BM * 64];
  __shared__ __align__(16) u16 Bs[BN * 64];
  const int z = blockIdx.z;
  const u16* A = Ab + (long)z * sAz;
  const u16* Bw = Bb + (long)z * sBz;
  const int m0 = blockIdx.x * BM;
  const int n0 = blockIdx.y * BN;
  const int tid = threadIdx.x;
  const int l = tid & 63;
  const int wv = tid >> 6;
  constexpr int WM = BM / 2, WN = BN / 2;
  constexpr int FM = WM / 16, FN = WN / 16;
  const int wm0 = (wv >> 1) * WM, wn0 = (wv & 1) * WN;
  const int lrow = l & 15, lk = (l >> 4) * 8;
  constexpr int GA = BM / 32, GB = BN / 32;   // 16B gloads per thread per tile
  int gA[GA], gB[GB];
#pragma unroll
  for (int q = 0; q < GA; ++q) {
    int d = (q * 256 + tid) * 16;
    int bb = swz(d);
    gA[q] = (m0 + (bb >> 7)) * K + ((bb & 127) >> 1);
  }
#pragma unroll
  for (int q = 0; q < GB; ++q) {
    int d = (q * 256 + tid) * 16;
    int bb = swz(d);
    gB[q] = (n0 + (bb >> 7)) * K + ((bb & 127) >> 1);
  }
  int aOff[FM][2], bOff[FN][2];
#pragma unroll
  for (int m = 0; m < FM; ++m)
#pragma unroll
    for (int kk = 0; kk < 2; ++kk)
      aOff[m][kk] = swz(((wm0 + m * 16 + lrow) << 7) + (kk << 6) + (lk << 1));
#pragma unroll
  for (int n = 0; n < FN; ++n)
#pragma unroll
    for (int kk = 0; kk < 2; ++kk)
      bOff[n][kk] = swz(((wn0 + n * 16 + lrow) << 7) + (kk << 6) + (lk << 1));
  f32x4 acc[FM][FN] = {};
  for (int k0 = 0; k0 < K; k0 += 64) {
    __syncthreads();
#pragma unroll
    for (int q = 0; q < GA; ++q)
      gload16(&A[(long)gA[q] + k0], (u16*)((char*)As + (q * 256 + tid) * 16));
#pragma unroll
    for (int q = 0; q < GB; ++q)
      gload16(&Bw[(long)gB[q] + k0], (u16*)((char*)Bs + (q * 256 + tid) * 16));
    __syncthreads();   // drains vmcnt -> LDS tile complete
#pragma unroll
    for (int kk = 0; kk < 2; ++kk) {
      s16x8 af[FM], bfr[FN];
#pragma unroll
      for (int m = 0; m < FM; ++m) af[m] = *(const s16x8*)((const char*)As + aOff[m][kk]);
#pragma unroll
      for (int n = 0; n < FN; ++n) bfr[n] = *(const s16x8*)((const char*)Bs + bOff[n][kk]);
#pragma unroll
      for (int m = 0; m < FM; ++m)
#pragma unroll
        for (int n = 0; n < FN; ++n)
          acc[m][n] = __builtin_amdgcn_mfma_f32_16x16x32_bf16(af[m], bfr[n], acc[m][n], 0, 0, 0);
    }
  }
#pragma unroll
  for (int m = 0; m < FM; ++m) {
#pragma unroll
    for (int n = 0; n < FN; ++n) {
      const int j = n0 + wn0 + n * 16 + lrow;
#pragma unroll
      for (int q = 0; q < 4; ++q) {
        const int i = m0 + wm0 + m * 16 + (l >> 4) * 4 + q;
        const long off = (long)i * N + j;
        float v = acc[m][n][q];
        if constexpr (EPI == 0) {
          ((float*)Ob + (long)z * sOz)[off] = v;
        } else if constexpr (EPI == 1) {
          ((u16*)Ob + (long)z * sOz)[off] = f2b(tanhf(v));
        } else if constexpr (EPI == 2) {
          float val = b2f(xB[off]) + b2f(dxB[off]) * (llb[(long)z * N + j] + v);
          ((u16*)Ob + (long)z * sOz)[off] = f2b(val);
        } else if constexpr (EPI == 3) {
          ((float*)Ob + (long)z * sOz)[off] = expf(-expf(llb[j] + v));
        } else {
          ((u16*)Ob + (long)z * sOz)[off] = f2b(v);
        }
      }
    }
  }
}

// ---------------- S1: chunk-local WKV scan, LDS-staged, 8 waves/block ----------------
// Whole chunk (r,k,v bf16 + w f32 = 40KB) bulk-staged to LDS; wave q owns state
// rows [8q, 8q+8) as f32x2[4] (packed v_pk_fma_f32 path). Wave0: rtil+A-product;
// wave1: u-term (folds into its partial). Partial y -> 8 bf16 buffers.
__global__ __launch_bounds__(512) void scan_local(
    const u16* __restrict__ rP, const u16* __restrict__ kP,
    const u16* __restrict__ vP, const float* __restrict__ wP,
    const float* __restrict__ uP, Ptr8 YS,
    u16* __restrict__ rtil, float* __restrict__ SL, float* __restrict__ AC) {
  __shared__ __align__(16) u16 Rs[64 * 64];
  __shared__ __align__(16) u16 Ks[64 * 64];
  __shared__ __align__(16) u16 Vs[64 * 64];
  __shared__ __align__(16) float Ws[64 * 64];
  const int bhc = blockIdx.x;
  const int c = bhc & (NCH - 1), h = (bhc >> 4) & (NH - 1), b = bhc >> 8;
  const int tid = threadIdx.x;
  const int j = tid & 63;
  const int qu = tid >> 6;                 // wave id 0..7
  const long base0 = ((long)(b * TTOK + c * CLEN) << 10) + h * HD;
  // ---- bulk stage chunk into LDS ----
  {
    int t = tid >> 3, off = (tid & 7) * 8;     // 512 x 16B chunks each
    gload16(&rP[base0 + (long)t * DD + off], (u16*)Rs + tid * 8);
    gload16(&kP[base0 + (long)t * DD + off], (u16*)Ks + tid * 8);
    gload16(&vP[base0 + (long)t * DD + off], (u16*)Vs + tid * 8);
  }
#pragma unroll
  for (int q = 0; q < 2; ++q) {            // w: 1024 x 16B chunks
    int cidx = q * 512 + tid;
    int t = cidx >> 4, off = (cidx & 15) * 4;
    __builtin_amdgcn_global_load_lds((const AS1 u32*)&wP[base0 + (long)t * DD + off],
                                     (AS3 u32*)((float*)Ws + cidx * 4), 16, 0, 0);
  }
  __syncthreads();                          // vmcnt(0) drain -> LDS ready
  const int so = qu * 8;
  f32x2 s2[4] = {};
  float Aj = 1.f;
  const float uj = (qu == 1) ? uP[h * HD + j] : 0.f;
  long base = base0;
  u16* __restrict__ ysel =
      qu == 0 ? YS.p[0] : qu == 1 ? YS.p[1] : qu == 2 ? YS.p[2] : qu == 3 ? YS.p[3] :
      qu == 4 ? YS.p[4] : qu == 5 ? YS.p[5] : qu == 6 ? YS.p[6] : YS.p[7];
  for (int tt = 0; tt < CLEN; ++tt) {
    const int ro = tt * 64 + so;
    u32x4 ra = *(const u32x4*)&Rs[ro];       // wave-uniform addr -> broadcast
    u32x4 ka = *(const u32x4*)&Ks[ro];
    f32x2 wv2[4];
#pragma unroll
    for (int e = 0; e < 4; ++e) wv2[e] = *(const f32x2*)&Ws[ro + 2 * e];
    const float vj = b2f(Vs[tt * 64 + j]);
    const f32x2 vj2 = {vj, vj};
    f32x2 y2 = {0.f, 0.f};
#pragma unroll
    for (int e = 0; e < 4; ++e) {
      const u32 pr = ra[e], pk = ka[e];
      f32x2 r01; r01[0] = ubit(pr << 16); r01[1] = ubit(pr & 0xffff0000u);
      f32x2 k01; k01[0] = ubit(pk << 16); k01[1] = ubit(pk & 0xffff0000u);
      y2 = __builtin_elementwise_fma(r01, s2[e], y2);
      s2[e] = __builtin_elementwise_fma(wv2[e], s2[e], k01 * vj2);
    }
    float y = y2[0] + y2[1];
    if (qu == 0) {                           // rtil + decay product
      const float rj = b2f(Rs[tt * 64 + j]);
      const float wj = Ws[tt * 64 + j];
      rtil[base + j] = f2b(rj * Aj);         // r_t * A_{t-1}
      Aj *= wj;
    } else if (qu == 1) {                    // u-term -> this wave's partial
      const float rj = b2f(Rs[tt * 64 + j]);
      const float kj = b2f(Ks[tt * 64 + j]);
      float al = rj * uj * kj;
#pragma unroll
      for (int msk = 1; msk < 64; msk <<= 1) al += __shfl_xor(al, msk, 64);
      y = fmaf(al, vj, y);
    }
    ysel[base + j] = f2b(y);
    base += DD;
  }
#pragma unroll
  for (int e = 0; e < 4; ++e) {
    SL[((long)bhc * 64 + so + 2 * e) * 64 + j] = s2[e][0];
    SL[((long)bhc * 64 + so + 2 * e + 1) * 64 + j] = s2[e][1];
  }
  if (qu == 0) AC[(long)bhc * 64 + j] = Aj;
}

// ---------------- S2a: propagate chunk-boundary states; overwrite SL[c] with S_in(c) ----------------
__global__ __launch_bounds__(256) void scan_prop(
    float* __restrict__ SL, const float* __restrict__ AC,
    const float* __restrict__ initS, float* __restrict__ st1) {
  const int bh = blockIdx.x >> 2;          // 64 bh
  const int jq = blockIdx.x & 3;
  const int h = bh & (NH - 1);
  const int i = threadIdx.x >> 2;
  const int jo = jq * 16 + (threadIdx.x & 3) * 4;
  f32x4 sin4 = *(const f32x4*)(initS + ((long)h * 64 + i) * 64 + jo);
  for (int cc = 0; cc < NCH; ++cc) {
    const long bhc = (long)bh * NCH + cc;
    f32x4* slp = (f32x4*)(SL + (bhc * 64 + i) * 64 + jo);
    const float Ai = AC[bhc * 64 + i];
    f32x4 sl = *slp;
    *slp = sin4;                           // S_in(c) for S2b
    sin4 = Ai * sin4 + sl;
  }
  *(f32x4*)(st1 + ((long)bh * 64 + i) * 64 + jo) = sin4;
}

// ---------------- S2b: cross-chunk correction ysC = rtil @ S_in (store, f32) -------
__global__ __launch_bounds__(256) void scan_corr(
    const float* __restrict__ SL, const u16* __restrict__ rtil, float* __restrict__ ysC) {
  __shared__ __align__(16) float S[64 * 64];
  const int bhc = blockIdx.x;
  const int c = bhc & (NCH - 1), h = (bhc >> 4) & (NH - 1), b = bhc >> 8;
  const int tid = threadIdx.x;
  const f32x4* sp = (const f32x4*)(SL + (long)bhc * 4096);
  for (int q = tid; q < 1024; q += 256) ((f32x4*)S)[q] = sp[q];
  __syncthreads();
  const int t = tid >> 2, jg = (tid & 3) * 16;
  const long base = ((long)(b * TTOK + c * CLEN + t) * DD) + h * HD;
  f32x4 yacc[4] = {};
  const u16* rp = rtil + base;
#pragma unroll 8
  for (int i = 0; i < 64; ++i) {
    const float r = b2f(rp[i]);
    const f32x4* srow = (const f32x4*)&S[i * 64 + jg];
#pragma unroll
    for (int e = 0; e < 4; ++e) yacc[e] += r * srow[e];
  }
  f32x4* yp = (f32x4*)(ysC + base + jg);
#pragma unroll
  for (int e = 0; e < 4; ++e) yp[e] = yacc[e];
}

// ---------------- GroupNorm(hd=64) * SiLU(g) -> o (bf16) ----------------
__global__ __launch_bounds__(256) void ln_silu(
    CPtr8 P, const float* __restrict__ ysC,
    const u16* __restrict__ gP,
    const float* __restrict__ lnw, const float* __restrict__ lnb,
    u16* __restrict__ oB) {
  const int ridx = blockIdx.x * 4 + (threadIdx.x >> 6);   // (token*16 + h)
  const int lane = threadIdx.x & 63;
  const long basem = (long)ridx * 64;
  float y = ysC[basem + lane];
#pragma unroll
  for (int q = 0; q < 8; ++q) y += b2f(P.p[q][basem + lane]);
  float su = y, sq = y * y;
#pragma unroll
  for (int msk = 1; msk < 64; msk <<= 1) {
    su += __shfl_xor(su, msk, 64);
    sq += __shfl_xor(sq, msk, 64);
  }
  const float mean = su * (1.f / 64.f);
  const float var = sq * (1.f / 64.f) - mean * mean;
  const float rs = rsqrtf(var + 1e-5f);
  const float g = b2f(gP[basem + lane]);
  const float silu = g / (1.f + expf(-g));
  const float val = silu * ((y - mean) * rs * lnw[lane] + lnb[lane]);
  oB[basem + lane] = f2b(val);
}

// ---------------- launcher ----------------
extern "C" void kernel_launch(void* const* d_in, const int* in_sizes, int n_in,
                              void* d_out, int out_size, void* d_ws, size_t ws_size,
                              hipStream_t stream) {
  const float* x   = (const float*)d_in[0];
  const float* xw  = (const float*)d_in[1];
  const float* rW  = (const float*)d_in[2];
  const float* kW  = (const float*)d_in[3];
  const float* vW  = (const float*)d_in[4];
  const float* gW  = (const float*)d_in[5];
  const float* r_la = (const float*)d_in[6],  *r_lb = (const float*)d_in[7],  *r_ll = (const float*)d_in[8];
  const float* k_la = (const float*)d_in[9],  *k_lb = (const float*)d_in[10], *k_ll = (const float*)d_in[11];
  const float* v_la = (const float*)d_in[12], *v_lb = (const float*)d_in[13], *v_ll = (const float*)d_in[14];
  const float* g_la = (const float*)d_in[15], *g_lb = (const float*)d_in[16], *g_ll = (const float*)d_in[17];
  const float* d_la = (const float*)d_in[18], *d_lb = (const float*)d_in[19], *d_ll = (const float*)d_in[20];
  const float* lnw = (const float*)d_in[21];
  const float* lnb = (const float*)d_in[22];
  const float* oW  = (const float*)d_in[23];
  const float* initS = (const float*)d_in[24];
  const float* uP  = (const float*)d_in[25];
  float* out = (float*)d_out;

  // workspace layout (~183 MB; 8 bf16 partial-ys buffers overlay dead regions)
  char* ws = (char*)d_ws;
  u16*   W_all  = (u16*)(ws + 0);                  // [5][1024][1024] bf16 (r,k,v,g,o)
  u16*   la_all = (u16*)(ws + 10485760);           // [5][64][1024]
  u16*   lb_all = (u16*)(ws + 11141120);           // [5][1024][64]
  float* ll_all = (float*)(ws + 11796480);         // [5][1024]
  u16*   lerpx  = (u16*)(ws + 11816960);           // [4096][1024] bf16 (dead after lora1)
  u16*   xB     = (u16*)(ws + 20205568);           // [4096][1024] bf16 (dead after z-stage2)
  u16*   dxB    = (u16*)(ws + 28594176);           // [4096][1024] bf16 (dead after z-stage2)
  u16*   t1_all = (u16*)(ws + 36982784);           // [5][4096][64] bf16
  u16*   z_all  = (u16*)(ws + 39604224);           // [5][4096][1024] bf16 (dead after projections)
  u16*   rkvg   = (u16*)(ws + 81547264);           // [4][4096][1024] bf16
  float* wbuf   = (float*)(ws + 115101696);        // [4096][1024] f32 (dead after scan_local)
  u16*   rtil   = (u16*)(ws + 131878912);          // [4096][1024] bf16
  float* SL     = (float*)(ws + 140267520);        // [1024][64][64] f32
  float* AC     = (float*)(ws + 157044736);        // [1024][64] f32
  u16*   ys0p   = (u16*)(ws + 157306880);          // [4096][1024] bf16 partial
  u16*   oB     = (u16*)(ws + 174084096);          // [4096][1024] bf16
  float* ysC    = (float*)(ws + 115101696);        // overlay: wbuf (f32 correction)

  Ptr8 YS;
  YS.p[0] = ys0p;
  YS.p[1] = (u16*)(ws + 11816960);                 // overlay: lerpx
  YS.p[2] = (u16*)(ws + 20205568);                 // overlay: xB
  YS.p[3] = (u16*)(ws + 28594176);                 // overlay: dxB
  YS.p[4] = (u16*)(ws + 39604224);                 // overlay: z_all[0]
  YS.p[5] = (u16*)(ws + 47992832);                 // overlay: z_all[1]
  YS.p[6] = (u16*)(ws + 56381440);                 // overlay: z_all[2]
  YS.p[7] = (u16*)(ws + 64770048);                 // overlay: z_all[3]

  convW<<<5120, 256, 0, stream>>>(rW, kW, vW, gW, oW, W_all);
  convLora<<<645, 256, 0, stream>>>(r_la, k_la, v_la, g_la, d_la,
                                    r_lb, k_lb, v_lb, g_lb, d_lb,
                                    r_ll, k_ll, v_ll, g_ll, d_ll,
                                    la_all, lb_all, ll_all);
  prep<<<4096, 256, 0, stream>>>(x, xw, lerpx, xB, dxB);

  // LoRA stage 1 (all 5): t1 = tanh(lerpx @ la^T)      [4096 x 64]
  gemm2<64, 64, 1><<<dim3(64, 1, 5), 256, 0, stream>>>(
      lerpx, 0L, la_all, 65536L, (void*)t1_all, 262144L, nullptr, nullptr, nullptr, MT, 64, 1024);
  // LoRA stage 2 (all 5): z = bf16(x + dx*(ll + t1 @ lb^T))   [4096 x 1024]
  gemm2<128, 128, 2><<<dim3(32, 8, 5), 256, 0, stream>>>(
      t1_all, 262144L, lb_all, 65536L, (void*)z_all, 4194304L, ll_all, xB, dxB, MT, 1024, 64);
  // d-outer stage 1: t2 = tanh(z_d @ d_la^T)
  gemm2<64, 64, 1><<<dim3(64, 1, 1), 256, 0, stream>>>(
      z_all + 4L * 4194304, 0L, la_all + 4L * 65536, 0L, (void*)t1_all, 0L, nullptr, nullptr, nullptr, MT, 64, 1024);
  // d-outer stage 2: w = exp(-exp(d_ll + t2 @ d_lb^T))  (f32)
  gemm2<128, 128, 3><<<dim3(32, 8, 1), 256, 0, stream>>>(
      t1_all, 0L, lb_all + 4L * 65536, 0L, (void*)wbuf, 0L, ll_all + 4096, nullptr, nullptr, MT, 1024, 64);
  // projections r,k,v,g = z @ W^T (bf16 out)
  gemm2<128, 128, 4><<<dim3(32, 8, 4), 256, 0, stream>>>(
      z_all, 4194304L, W_all, 1048576L, (void*)rkvg, 4194304L, nullptr, nullptr, nullptr, MT, 1024, 1024);

  // chunked WKV scan
  scan_local<<<1024, 512, 0, stream>>>(rkvg, rkvg + 4194304L, rkvg + 2L * 4194304, wbuf,
                                       uP, YS, rtil, SL, AC);
  scan_prop<<<256, 256, 0, stream>>>(SL, AC, initS, out + 4194304);
  scan_corr<<<1024, 256, 0, stream>>>(SL, rtil, ysC);

  // o = silu(g) * groupnorm(y); out = o @ oW^T
  CPtr8 YSc;
  for (int q = 0; q < 8; ++q) YSc.p[q] = YS.p[q];
  ln_silu<<<16384, 256, 0, stream>>>(YSc, ysC, rkvg + 3L * 4194304, lnw, lnb, oB);
  gemm2<128, 128, 0><<<dim3(32, 8, 1), 256, 0, stream>>>(
      oB, 0L, W_all + 4L * 1048576, 0L, (void*)out, 0L, nullptr, nullptr, nullptr, MT, 1024, 1024);
}